// Round 1
// baseline (342.989 us; speedup 1.0000x reference)
//
#include <hip/hip_runtime.h>
#include <cstdint>
#include <cstddef>

typedef unsigned short u16;
typedef __attribute__((ext_vector_type(8))) short short8;
typedef __attribute__((ext_vector_type(4))) float f32x4;

#define GLOBAL_AS(p) ((const __attribute__((address_space(1))) void*)(p))
#define LDS_AS(p)    ((__attribute__((address_space(3))) void*)(p))

__device__ __forceinline__ float bf2f(u16 u){
  union { uint32_t u; float f; } c; c.u = ((uint32_t)u) << 16; return c.f;
}
__device__ __forceinline__ u16 f2bf(float f){
  union { float f; uint32_t u; } c; c.f = f;
  uint32_t r = c.u + 0x7fffu + ((c.u >> 16) & 1u);
  return (u16)(r >> 16);
}

// ---------------- LayerNorm + cast to bf16 (one block per 768-elem row) ----
__global__ __launch_bounds__(256) void ln_cast(const float* __restrict__ x,
    const float* __restrict__ g, const float* __restrict__ bta,
    u16* __restrict__ y)
{
  const size_t row = blockIdx.x;
  const float* xr = x + row * 768;
  const int t = threadIdx.x;
  float v0 = xr[t], v1 = xr[t+256], v2 = xr[t+512];
  float s = v0+v1+v2;
  float q = v0*v0 + v1*v1 + v2*v2;
  #pragma unroll
  for (int o=1;o<64;o<<=1){ s += __shfl_xor(s,o); q += __shfl_xor(q,o); }
  __shared__ float rs_[4], rq_[4];
  if ((t & 63) == 0){ rs_[t>>6] = s; rq_[t>>6] = q; }
  __syncthreads();
  s = rs_[0]+rs_[1]+rs_[2]+rs_[3];
  q = rq_[0]+rq_[1]+rq_[2]+rq_[3];
  const float m = s * (1.f/768.f);
  const float var = q * (1.f/768.f) - m*m;
  const float rstd = rsqrtf(var + 1e-6f);
  u16* yr = y + row * 768;
  yr[t]     = f2bf((v0-m)*rstd*g[t]     + bta[t]);
  yr[t+256] = f2bf((v1-m)*rstd*g[t+256] + bta[t+256]);
  yr[t+512] = f2bf((v2-m)*rstd*g[t+512] + bta[t+512]);
}

// ---------------- transpose+cast: out[n][k] = bf16(in[k*ld + n]), k<768 ----
__global__ __launch_bounds__(256) void tcast(const float* __restrict__ in,
    int ld, int ncnt, u16* __restrict__ out)
{
  __shared__ float tile[32][33];
  const int tx = threadIdx.x & 31, ty = threadIdx.x >> 5;
  const int n0 = blockIdx.x * 32, k0 = blockIdx.y * 32;
  #pragma unroll
  for (int i=0;i<4;i++){
    int k = k0 + ty + 8*i, n = n0 + tx;
    tile[ty+8*i][tx] = (n < ncnt) ? in[(size_t)k*ld + n] : 0.f;
  }
  __syncthreads();
  #pragma unroll
  for (int i=0;i<4;i++){
    int n = n0 + ty + 8*i, k = k0 + tx;
    if (n < ncnt) out[(size_t)n*768 + k] = f2bf(tile[tx][ty+8*i]);
  }
}

__global__ void pack_bsa(const float* __restrict__ bs, const float* __restrict__ ba,
                         float* __restrict__ bsa)
{
  int t = threadIdx.x;
  bsa[t] = (t < 144) ? bs[t] : ((t < 216) ? ba[t-144] : 0.f);
}

// ---------------- bf16 MFMA GEMM: C[M,N] = A[M,K] * Bt[N,K]^T + bias -------
// 128x128 tile, BK=32, 256 threads (4 waves, 2x2 wave grid, 64x64 per wave).
// OUT_KIND: 0 = bf16 out, 1 = f32 out, 2 = f32 out + residual
template<int OUT_KIND>
__global__ __launch_bounds__(256) void gemm_bt(
    const u16* __restrict__ A, const u16* __restrict__ Bt,
    const float* __restrict__ bias, const float* __restrict__ res,
    void* __restrict__ Cout, int M, int N, int K)
{
  __shared__ u16 sA[128*32];
  __shared__ u16 sB[128*32];
  const int m0 = blockIdx.y * 128, n0 = blockIdx.x * 128;
  const int t = threadIdx.x;
  const int w = t >> 6, lane = t & 63;
  const int wr = w >> 1, wc = w & 1;

  f32x4 acc[4][4];
  #pragma unroll
  for (int mi=0;mi<4;mi++)
    #pragma unroll
    for (int ni=0;ni<4;ni++)
      acc[mi][ni] = (f32x4){0.f,0.f,0.f,0.f};

  // staging: wave w covers rows [w*32, w*32+32) of each 128x32 tile,
  // two global_load_lds(16B) per operand; lane l -> row w*32+i*16+(l>>2), col (l&3)*8
  const int rST = w*32 + (lane>>2);
  const int cST = (lane&3)*8;
  const u16* gA = A + (size_t)(m0 + rST)*K + cST;
  const u16* gB = Bt + (size_t)(n0 + rST)*K + cST;
  u16* lA = sA + (w*32)*32;   // wave-uniform LDS base
  u16* lB = sB + (w*32)*32;
  const int kb = (lane>>4)*8;

  for (int k0 = 0; k0 < K; k0 += 32) {
    __syncthreads();
    __builtin_amdgcn_global_load_lds(GLOBAL_AS(gA),            LDS_AS(lA),          16, 0, 0);
    __builtin_amdgcn_global_load_lds(GLOBAL_AS(gA + 16*(size_t)K), LDS_AS(lA + 16*32), 16, 0, 0);
    __builtin_amdgcn_global_load_lds(GLOBAL_AS(gB),            LDS_AS(lB),          16, 0, 0);
    __builtin_amdgcn_global_load_lds(GLOBAL_AS(gB + 16*(size_t)K), LDS_AS(lB + 16*32), 16, 0, 0);
    gA += 32; gB += 32;
    __syncthreads();

    short8 af[4], bfr[4];
    #pragma unroll
    for (int mi=0;mi<4;mi++)
      af[mi] = *(const short8*)&sA[(wr*64 + mi*16 + (lane&15))*32 + kb];
    #pragma unroll
    for (int ni=0;ni<4;ni++)
      bfr[ni] = *(const short8*)&sB[(wc*64 + ni*16 + (lane&15))*32 + kb];
    #pragma unroll
    for (int mi=0;mi<4;mi++)
      #pragma unroll
      for (int ni=0;ni<4;ni++)
        acc[mi][ni] = __builtin_amdgcn_mfma_f32_16x16x32_bf16(af[mi], bfr[ni], acc[mi][ni], 0, 0, 0);
  }

  // epilogue: D frag mapping col=lane&15, row=(lane>>4)*4+reg  [verified m89]
  #pragma unroll
  for (int ni=0;ni<4;ni++){
    const int col = n0 + wc*64 + ni*16 + (lane&15);
    const float bc = bias[col];
    #pragma unroll
    for (int mi=0;mi<4;mi++){
      const int row0 = m0 + wr*64 + mi*16 + (lane>>4)*4;
      #pragma unroll
      for (int r=0;r<4;r++){
        float v = acc[mi][ni][r] + bc;
        size_t off = (size_t)(row0+r)*N + col;
        if constexpr (OUT_KIND == 0)      ((u16*)Cout)[off] = f2bf(v);
        else if constexpr (OUT_KIND == 1) ((float*)Cout)[off] = v;
        else                              ((float*)Cout)[off] = v + res[off];
      }
    }
  }
}

// ---------------- deformable sampling + attention-weighted accumulate ------
// one 128-thread block per (b,q). offattn row: [0..143]=offsets, [144..215]=logits
#define NQ_ 4096
#define LV_ 21504

__global__ __launch_bounds__(128) void sample_kernel(
    const float* __restrict__ offattn, const float* __restrict__ refp,
    const u16* __restrict__ value, u16* __restrict__ accb)
{
  const int bq = blockIdx.x;
  const int b = bq >> 12;
  const float* row = offattn + (size_t)bq * 256;
  __shared__ float s_w[4][72];
  __shared__ int   s_idx[4][72];
  __shared__ float s_at[72];
  __shared__ float s_lg[72];
  const int t = threadIdx.x;

  if (t < 72) {
    const int s = t, j = s % 12, l = j >> 2;
    s_lg[s] = row[144 + s];
    const float Wf = (l==0) ? 128.f : ((l==1) ? 64.f : 32.f);
    const int   Wi = (l==0) ? 128   : ((l==1) ? 64   : 32);
    const int   st = (l==0) ? 0     : ((l==1) ? 16384 : 20480);
    const float rx = refp[((size_t)bq*3 + l)*2 + 0];
    const float ry = refp[((size_t)bq*3 + l)*2 + 1];
    // loc = ref + off/(W,H); px = loc*W - 0.5 = ref*W + off - 0.5  (H==W per level)
    const float px = rx*Wf + row[2*s]   - 0.5f;
    const float py = ry*Wf + row[2*s+1] - 0.5f;
    const float x0f = floorf(px), y0f = floorf(py);
    const int x0 = (int)x0f, y0 = (int)y0f;
    const float fx = px - x0f, fy = py - y0f;
    #pragma unroll
    for (int c=0;c<4;c++){
      const int dx = c & 1, dy = c >> 1;
      const int ix = x0 + dx, iy = y0 + dy;
      const float wgt = (dx ? fx : 1.f-fx) * (dy ? fy : 1.f-fy);
      const bool ok = (ix >= 0) && (ix < Wi) && (iy >= 0) && (iy < Wi);
      const int cx = min(max(ix,0),Wi-1), cy = min(max(iy,0),Wi-1);
      s_w[c][s]   = ok ? wgt : 0.f;
      s_idx[c][s] = st + cy*Wi + cx;
    }
  }
  __syncthreads();
  if (t < 6) {
    float m = s_lg[t*12];
    #pragma unroll
    for (int j2=1;j2<12;j2++) m = fmaxf(m, s_lg[t*12+j2]);
    float e[12]; float sum = 0.f;
    #pragma unroll
    for (int j2=0;j2<12;j2++){ e[j2] = __expf(s_lg[t*12+j2]-m); sum += e[j2]; }
    const float inv = 1.f/sum;
    #pragma unroll
    for (int j2=0;j2<12;j2++) s_at[t*12+j2] = e[j2]*inv;
  }
  __syncthreads();

  const u16* vb = value + (size_t)b * LV_ * 768;
  u16* ob = accb + (size_t)bq * 768;
  #pragma unroll
  for (int i=0;i<3;i++){
    const int pi = t + 128*i;
    const int h = pi >> 6, dp = pi & 63;
    const int col = h*128 + dp*2;
    float ax = 0.f, ay = 0.f;
    for (int j2=0;j2<12;j2++){
      const int s = h*12 + j2;
      float sx = 0.f, sy = 0.f;
      #pragma unroll
      for (int c=0;c<4;c++){
        const float wgt = s_w[c][s];          // wave-uniform
        if (wgt != 0.f) {
          const uint32_t u = *(const uint32_t*)(vb + (size_t)s_idx[c][s]*768 + col);
          sx += wgt * bf2f((u16)(u & 0xffffu));
          sy += wgt * bf2f((u16)(u >> 16));
        }
      }
      const float at = s_at[s];
      ax += at * sx; ay += at * sy;
    }
    const uint32_t o = ((uint32_t)f2bf(ay) << 16) | (uint32_t)f2bf(ax);
    *(uint32_t*)(ob + col) = o;
  }
}

// ---------------------------------------------------------------------------
extern "C" void kernel_launch(void* const* d_in, const int* in_sizes, int n_in,
                              void* d_out, int out_size, void* d_ws, size_t ws_size,
                              hipStream_t stream) {
  (void)in_sizes; (void)n_in; (void)out_size; (void)ws_size;
  const float* query = (const float*)d_in[0];
  const float* refp  = (const float*)d_in[1];
  const float* feat  = (const float*)d_in[2];
  const float* qn_g  = (const float*)d_in[3];
  const float* qn_b  = (const float*)d_in[4];
  const float* fn_g  = (const float*)d_in[5];
  const float* fn_b  = (const float*)d_in[6];
  const float* Wv    = (const float*)d_in[7];
  const float* bv    = (const float*)d_in[8];
  const float* Ws    = (const float*)d_in[9];
  const float* bs    = (const float*)d_in[10];
  const float* Wa    = (const float*)d_in[11];
  const float* ba    = (const float*)d_in[12];
  const float* Wo    = (const float*)d_in[13];
  const float* bo    = (const float*)d_in[14];
  float* out = (float*)d_out;

  // workspace layout (bytes)
  constexpr size_t SZ_FLN  = (size_t)43008*768*2;  // 66,060,288
  constexpr size_t SZ_QLN  = (size_t)8192*768*2;   // 12,582,912
  constexpr size_t SZ_W    = (size_t)768*768*2;    // 1,179,648
  constexpr size_t SZ_WSAT = (size_t)256*768*2;    // 393,216
  char* ws = (char*)d_ws;
  u16*  fln   = (u16*)(ws);
  u16*  value = (u16*)(ws + SZ_FLN);
  u16*  qln   = (u16*)(ws + 2*SZ_FLN);
  u16*  Wvt   = (u16*)(ws + 2*SZ_FLN + SZ_QLN);
  u16*  Wot   = (u16*)(ws + 2*SZ_FLN + SZ_QLN + SZ_W);
  u16*  Wsat  = (u16*)(ws + 2*SZ_FLN + SZ_QLN + 2*SZ_W);
  float* bsa  = (float*)(ws + 2*SZ_FLN + SZ_QLN + 2*SZ_W + SZ_WSAT);
  float* offattn = (float*)fln;   // alias: fln dead after value GEMM
  u16*   accb    = qln;           // alias: qln dead after off/attn GEMM

  // 1) LayerNorms -> bf16
  ln_cast<<<8192, 256, 0, stream>>>(query, qn_g, qn_b, qln);
  ln_cast<<<43008, 256, 0, stream>>>(feat, fn_g, fn_b, fln);

  // 2) weight pre-transpose/cast (Bt layouts [N][K])
  tcast<<<dim3(24,24), 256, 0, stream>>>(Wv, 768, 768, Wvt);
  tcast<<<dim3(24,24), 256, 0, stream>>>(Wo, 768, 768, Wot);
  hipMemsetAsync(Wsat, 0, SZ_WSAT, stream);
  tcast<<<dim3(5,24), 256, 0, stream>>>(Ws, 144, 144, Wsat);
  tcast<<<dim3(3,24), 256, 0, stream>>>(Wa, 72, 72, Wsat + (size_t)144*768);
  pack_bsa<<<1, 256, 0, stream>>>(bs, ba, bsa);

  // 3) value = LN(feat) @ Wv + bv  -> bf16 [2*21504, 768]
  gemm_bt<0><<<dim3(6,336), 256, 0, stream>>>(fln, Wvt, bv, nullptr, value, 43008, 768, 768);

  // 4) off/attn logits = LN(query) @ [Ws|Wa] + [bs|ba] -> f32 [8192, 256]
  gemm_bt<1><<<dim3(2,64), 256, 0, stream>>>(qln, Wsat, bsa, nullptr, offattn, 8192, 256, 768);

  // 5) deformable sampling + softmax-weighted accumulation -> bf16 [8192, 768]
  sample_kernel<<<8192, 128, 0, stream>>>(offattn, refp, value, accb);

  // 6) out = acc @ Wo + bo + query -> f32
  gemm_bt<2><<<dim3(6,64), 256, 0, stream>>>(accb, Wot, bo, query, out, 8192, 768, 768);
}

// Round 2
// 264.315 us; speedup vs baseline: 1.2977x; 1.2977x over previous
//
#include <hip/hip_runtime.h>
#include <cstdint>
#include <cstddef>

typedef unsigned short u16;
typedef __attribute__((ext_vector_type(8))) short short8;
typedef __attribute__((ext_vector_type(4))) float f32x4;
typedef __attribute__((ext_vector_type(4))) unsigned int u32x4;

#define GLOBAL_AS(p) ((const __attribute__((address_space(1))) void*)(p))
#define LDS_AS(p)    ((__attribute__((address_space(3))) void*)(p))

__device__ __forceinline__ float bf2f(u16 u){
  union { uint32_t u; float f; } c; c.u = ((uint32_t)u) << 16; return c.f;
}
__device__ __forceinline__ float lo16(uint32_t u){
  union { uint32_t u; float f; } c; c.u = u << 16; return c.f;
}
__device__ __forceinline__ float hi16(uint32_t u){
  union { uint32_t u; float f; } c; c.u = u & 0xffff0000u; return c.f;
}
__device__ __forceinline__ u16 f2bf(float f){
  union { float f; uint32_t u; } c; c.f = f;
  uint32_t r = c.u + 0x7fffu + ((c.u >> 16) & 1u);
  return (u16)(r >> 16);
}

// ---------------- LayerNorm + cast to bf16 (one block per 768-elem row) ----
__global__ __launch_bounds__(256) void ln_cast(const float* __restrict__ x,
    const float* __restrict__ g, const float* __restrict__ bta,
    u16* __restrict__ y)
{
  const size_t row = blockIdx.x;
  const float* xr = x + row * 768;
  const int t = threadIdx.x;
  float v0 = xr[t], v1 = xr[t+256], v2 = xr[t+512];
  float s = v0+v1+v2;
  float q = v0*v0 + v1*v1 + v2*v2;
  #pragma unroll
  for (int o=1;o<64;o<<=1){ s += __shfl_xor(s,o); q += __shfl_xor(q,o); }
  __shared__ float rs_[4], rq_[4];
  if ((t & 63) == 0){ rs_[t>>6] = s; rq_[t>>6] = q; }
  __syncthreads();
  s = rs_[0]+rs_[1]+rs_[2]+rs_[3];
  q = rq_[0]+rq_[1]+rq_[2]+rq_[3];
  const float m = s * (1.f/768.f);
  const float var = q * (1.f/768.f) - m*m;
  const float rstd = rsqrtf(var + 1e-6f);
  u16* yr = y + row * 768;
  yr[t]     = f2bf((v0-m)*rstd*g[t]     + bta[t]);
  yr[t+256] = f2bf((v1-m)*rstd*g[t+256] + bta[t+256]);
  yr[t+512] = f2bf((v2-m)*rstd*g[t+512] + bta[t+512]);
}

// ---------------- transpose+cast: out[n][k] = bf16(in[k*ld + n]), k<768 ----
__global__ __launch_bounds__(256) void tcast(const float* __restrict__ in,
    int ld, int ncnt, u16* __restrict__ out)
{
  __shared__ float tile[32][33];
  const int tx = threadIdx.x & 31, ty = threadIdx.x >> 5;
  const int n0 = blockIdx.x * 32, k0 = blockIdx.y * 32;
  #pragma unroll
  for (int i=0;i<4;i++){
    int k = k0 + ty + 8*i, n = n0 + tx;
    tile[ty+8*i][tx] = (n < ncnt) ? in[(size_t)k*ld + n] : 0.f;
  }
  __syncthreads();
  #pragma unroll
  for (int i=0;i<4;i++){
    int n = n0 + ty + 8*i, k = k0 + tx;
    if (n < ncnt) out[(size_t)n*768 + k] = f2bf(tile[tx][ty+8*i]);
  }
}

__global__ void pack_bsa(const float* __restrict__ bs, const float* __restrict__ ba,
                         float* __restrict__ bsa)
{
  int t = threadIdx.x;
  bsa[t] = (t < 144) ? bs[t] : ((t < 216) ? ba[t-144] : 0.f);
}

// ---------------- bf16 MFMA GEMM: C[M,N] = A[M,K] * Bt[N,K]^T + bias -------
// 128x128 tile, BK=32, 256 threads (4 waves, 2x2 wave grid, 64x64 per wave).
// OUT_KIND: 0 = bf16 out, 1 = f32 out, 2 = f32 out + residual
template<int OUT_KIND>
__global__ __launch_bounds__(256) void gemm_bt(
    const u16* __restrict__ A, const u16* __restrict__ Bt,
    const float* __restrict__ bias, const float* __restrict__ res,
    void* __restrict__ Cout, int M, int N, int K)
{
  __shared__ u16 sA[128*32];
  __shared__ u16 sB[128*32];
  const int m0 = blockIdx.y * 128, n0 = blockIdx.x * 128;
  const int t = threadIdx.x;
  const int w = t >> 6, lane = t & 63;
  const int wr = w >> 1, wc = w & 1;

  f32x4 acc[4][4];
  #pragma unroll
  for (int mi=0;mi<4;mi++)
    #pragma unroll
    for (int ni=0;ni<4;ni++)
      acc[mi][ni] = (f32x4){0.f,0.f,0.f,0.f};

  const int rST = w*32 + (lane>>2);
  const int cST = (lane&3)*8;
  const u16* gA = A + (size_t)(m0 + rST)*K + cST;
  const u16* gB = Bt + (size_t)(n0 + rST)*K + cST;
  u16* lA = sA + (w*32)*32;   // wave-uniform LDS base
  u16* lB = sB + (w*32)*32;
  const int kb = (lane>>4)*8;

  for (int k0 = 0; k0 < K; k0 += 32) {
    __syncthreads();
    __builtin_amdgcn_global_load_lds(GLOBAL_AS(gA),               LDS_AS(lA),          16, 0, 0);
    __builtin_amdgcn_global_load_lds(GLOBAL_AS(gA + 16*(size_t)K), LDS_AS(lA + 16*32), 16, 0, 0);
    __builtin_amdgcn_global_load_lds(GLOBAL_AS(gB),               LDS_AS(lB),          16, 0, 0);
    __builtin_amdgcn_global_load_lds(GLOBAL_AS(gB + 16*(size_t)K), LDS_AS(lB + 16*32), 16, 0, 0);
    gA += 32; gB += 32;
    __syncthreads();

    short8 af[4], bfr[4];
    #pragma unroll
    for (int mi=0;mi<4;mi++)
      af[mi] = *(const short8*)&sA[(wr*64 + mi*16 + (lane&15))*32 + kb];
    #pragma unroll
    for (int ni=0;ni<4;ni++)
      bfr[ni] = *(const short8*)&sB[(wc*64 + ni*16 + (lane&15))*32 + kb];
    #pragma unroll
    for (int mi=0;mi<4;mi++)
      #pragma unroll
      for (int ni=0;ni<4;ni++)
        acc[mi][ni] = __builtin_amdgcn_mfma_f32_16x16x32_bf16(af[mi], bfr[ni], acc[mi][ni], 0, 0, 0);
  }

  #pragma unroll
  for (int ni=0;ni<4;ni++){
    const int col = n0 + wc*64 + ni*16 + (lane&15);
    const float bc = bias[col];
    #pragma unroll
    for (int mi=0;mi<4;mi++){
      const int row0 = m0 + wr*64 + mi*16 + (lane>>4)*4;
      #pragma unroll
      for (int r=0;r<4;r++){
        float v = acc[mi][ni][r] + bc;
        size_t off = (size_t)(row0+r)*N + col;
        if constexpr (OUT_KIND == 0)      ((u16*)Cout)[off] = f2bf(v);
        else if constexpr (OUT_KIND == 1) ((float*)Cout)[off] = v;
        else                              ((float*)Cout)[off] = v + res[off];
      }
    }
  }
}

// ---------------- deformable sampling + attention-weighted accumulate ------
// 192 threads/block, 2 queries/block. 96 threads per query; each thread owns
// 8 contiguous bf16 columns (dwordx4 gathers). Branchless: invalid corners
// have wgt==0 and clamped (safe) indices.
#define NQ_ 4096
#define LV_ 21504

__global__ __launch_bounds__(192) void sample_kernel(
    const float* __restrict__ offattn, const float* __restrict__ refp,
    const u16* __restrict__ value, u16* __restrict__ accb)
{
  __shared__ float s_w[2][4][72];
  __shared__ int   s_idx[2][4][72];
  __shared__ float s_at[2][72];
  const int t = threadIdx.x;

  if (t < 144) {
    const int qi = t / 72, s = t % 72;
    const int bq = blockIdx.x*2 + qi;
    const float* row = offattn + (size_t)bq * 256;
    const int j = s % 12, l = j >> 2;
    const float Wf = (l==0) ? 128.f : ((l==1) ? 64.f : 32.f);
    const int   Wi = (l==0) ? 128   : ((l==1) ? 64   : 32);
    const int   st = (l==0) ? 0     : ((l==1) ? 16384 : 20480);
    const float rx = refp[((size_t)bq*3 + l)*2 + 0];
    const float ry = refp[((size_t)bq*3 + l)*2 + 1];
    // loc = ref + off/(W,H); px = loc*W - 0.5 = ref*W + off - 0.5  (H==W per level)
    const float px = rx*Wf + row[2*s]   - 0.5f;
    const float py = ry*Wf + row[2*s+1] - 0.5f;
    const float x0f = floorf(px), y0f = floorf(py);
    const int x0 = (int)x0f, y0 = (int)y0f;
    const float fx = px - x0f, fy = py - y0f;
    #pragma unroll
    for (int c=0;c<4;c++){
      const int dx = c & 1, dy = c >> 1;
      const int ix = x0 + dx, iy = y0 + dy;
      const float wgt = (dx ? fx : 1.f-fx) * (dy ? fy : 1.f-fy);
      const bool ok = (ix >= 0) && (ix < Wi) && (iy >= 0) && (iy < Wi);
      const int cx = min(max(ix,0),Wi-1), cy = min(max(iy,0),Wi-1);
      s_w[qi][c][s]   = ok ? wgt : 0.f;
      s_idx[qi][c][s] = st + cy*Wi + cx;
    }
  } else if (t < 156) {
    const int u = t - 144, qi = u / 6, h = u % 6;
    const int bq = blockIdx.x*2 + qi;
    const float* lg = offattn + (size_t)bq * 256 + 144 + h*12;
    float m = lg[0];
    #pragma unroll
    for (int j2=1;j2<12;j2++) m = fmaxf(m, lg[j2]);
    float e[12]; float sum = 0.f;
    #pragma unroll
    for (int j2=0;j2<12;j2++){ e[j2] = __expf(lg[j2]-m); sum += e[j2]; }
    const float inv = 1.f/sum;
    #pragma unroll
    for (int j2=0;j2<12;j2++) s_at[qi][h*12+j2] = e[j2]*inv;
  }
  __syncthreads();

  const int qi = t / 96, tt = t % 96;
  const int bq = blockIdx.x*2 + qi;
  const int b = bq >> 12;
  const int cb = tt * 8;          // u16 column base
  const int h = cb >> 7;          // head
  const u16* vb = value + (size_t)b * LV_ * 768;

  float ax[8];
  #pragma unroll
  for (int k=0;k<8;k++) ax[k] = 0.f;

  #pragma unroll 2
  for (int j2=0;j2<12;j2++){
    const int s = h*12 + j2;
    const float at = s_at[qi][s];
    float sx[8];
    #pragma unroll
    for (int k=0;k<8;k++) sx[k] = 0.f;
    #pragma unroll
    for (int c=0;c<4;c++){
      const float wgt = s_w[qi][c][s];
      const u32x4 u = *(const u32x4*)(vb + (size_t)s_idx[qi][c][s]*768 + cb);
      sx[0] += wgt * lo16(u[0]); sx[1] += wgt * hi16(u[0]);
      sx[2] += wgt * lo16(u[1]); sx[3] += wgt * hi16(u[1]);
      sx[4] += wgt * lo16(u[2]); sx[5] += wgt * hi16(u[2]);
      sx[6] += wgt * lo16(u[3]); sx[7] += wgt * hi16(u[3]);
    }
    #pragma unroll
    for (int k=0;k<8;k++) ax[k] += at * sx[k];
  }

  u16* ob = accb + (size_t)bq * 768 + cb;
  u32x4 o;
  #pragma unroll
  for (int k=0;k<4;k++)
    o[k] = ((uint32_t)f2bf(ax[2*k+1]) << 16) | (uint32_t)f2bf(ax[2*k]);
  *(u32x4*)ob = o;
}

// ---------------------------------------------------------------------------
extern "C" void kernel_launch(void* const* d_in, const int* in_sizes, int n_in,
                              void* d_out, int out_size, void* d_ws, size_t ws_size,
                              hipStream_t stream) {
  (void)in_sizes; (void)n_in; (void)out_size; (void)ws_size;
  const float* query = (const float*)d_in[0];
  const float* refp  = (const float*)d_in[1];
  const float* feat  = (const float*)d_in[2];
  const float* qn_g  = (const float*)d_in[3];
  const float* qn_b  = (const float*)d_in[4];
  const float* fn_g  = (const float*)d_in[5];
  const float* fn_b  = (const float*)d_in[6];
  const float* Wv    = (const float*)d_in[7];
  const float* bv    = (const float*)d_in[8];
  const float* Ws    = (const float*)d_in[9];
  const float* bs    = (const float*)d_in[10];
  const float* Wa    = (const float*)d_in[11];
  const float* ba    = (const float*)d_in[12];
  const float* Wo    = (const float*)d_in[13];
  const float* bo    = (const float*)d_in[14];
  float* out = (float*)d_out;

  // workspace layout (bytes)
  constexpr size_t SZ_FLN  = (size_t)43008*768*2;  // 66,060,288
  constexpr size_t SZ_QLN  = (size_t)8192*768*2;   // 12,582,912
  constexpr size_t SZ_W    = (size_t)768*768*2;    // 1,179,648
  constexpr size_t SZ_WSAT = (size_t)256*768*2;    // 393,216
  char* ws = (char*)d_ws;
  u16*  fln   = (u16*)(ws);
  u16*  value = (u16*)(ws + SZ_FLN);
  u16*  qln   = (u16*)(ws + 2*SZ_FLN);
  u16*  Wvt   = (u16*)(ws + 2*SZ_FLN + SZ_QLN);
  u16*  Wot   = (u16*)(ws + 2*SZ_FLN + SZ_QLN + SZ_W);
  u16*  Wsat  = (u16*)(ws + 2*SZ_FLN + SZ_QLN + 2*SZ_W);
  float* bsa  = (float*)(ws + 2*SZ_FLN + SZ_QLN + 2*SZ_W + SZ_WSAT);
  float* offattn = (float*)fln;   // alias: fln dead after value GEMM
  u16*   accb    = qln;           // alias: qln dead after off/attn GEMM

  // 1) LayerNorms -> bf16
  ln_cast<<<8192, 256, 0, stream>>>(query, qn_g, qn_b, qln);
  ln_cast<<<43008, 256, 0, stream>>>(feat, fn_g, fn_b, fln);

  // 2) weight pre-transpose/cast (Bt layouts [N][K])
  tcast<<<dim3(24,24), 256, 0, stream>>>(Wv, 768, 768, Wvt);
  tcast<<<dim3(24,24), 256, 0, stream>>>(Wo, 768, 768, Wot);
  hipMemsetAsync(Wsat, 0, SZ_WSAT, stream);
  tcast<<<dim3(5,24), 256, 0, stream>>>(Ws, 144, 144, Wsat);
  tcast<<<dim3(3,24), 256, 0, stream>>>(Wa, 72, 72, Wsat + (size_t)144*768);
  pack_bsa<<<1, 256, 0, stream>>>(bs, ba, bsa);

  // 3) value = LN(feat) @ Wv + bv  -> bf16 [2*21504, 768]
  gemm_bt<0><<<dim3(6,336), 256, 0, stream>>>(fln, Wvt, bv, nullptr, value, 43008, 768, 768);

  // 4) off/attn logits = LN(query) @ [Ws|Wa] + [bs|ba] -> f32 [8192, 256]
  gemm_bt<1><<<dim3(2,64), 256, 0, stream>>>(qln, Wsat, bsa, nullptr, offattn, 8192, 256, 768);

  // 5) deformable sampling + softmax-weighted accumulation -> bf16 [8192, 768]
  sample_kernel<<<4096, 192, 0, stream>>>(offattn, refp, value, accb);

  // 6) out = acc @ Wo + bo + query -> f32
  gemm_bt<2><<<dim3(6,64), 256, 0, stream>>>(accb, Wot, bo, query, out, 8192, 768, 768);
}

// Round 3
// 250.000 us; speedup vs baseline: 1.3720x; 1.0573x over previous
//
#include <hip/hip_runtime.h>
#include <cstdint>
#include <cstddef>

typedef unsigned short u16;
typedef __attribute__((ext_vector_type(8))) short short8;
typedef __attribute__((ext_vector_type(4))) float f32x4;
typedef __attribute__((ext_vector_type(4))) unsigned int u32x4;

#define GLOBAL_AS(p) ((const __attribute__((address_space(1))) void*)(p))
#define LDS_AS(p)    ((__attribute__((address_space(3))) void*)(p))

__device__ __forceinline__ float bf2f(u16 u){
  union { uint32_t u; float f; } c; c.u = ((uint32_t)u) << 16; return c.f;
}
__device__ __forceinline__ float lo16(uint32_t u){
  union { uint32_t u; float f; } c; c.u = u << 16; return c.f;
}
__device__ __forceinline__ float hi16(uint32_t u){
  union { uint32_t u; float f; } c; c.u = u & 0xffff0000u; return c.f;
}
__device__ __forceinline__ u16 f2bf(float f){
  union { float f; uint32_t u; } c; c.f = f;
  uint32_t r = c.u + 0x7fffu + ((c.u >> 16) & 1u);
  return (u16)(r >> 16);
}

// ---------------- LayerNorm + cast to bf16 (one block per 768-elem row) ----
__global__ __launch_bounds__(256) void ln_cast(const float* __restrict__ x,
    const float* __restrict__ g, const float* __restrict__ bta,
    u16* __restrict__ y)
{
  const size_t row = blockIdx.x;
  const float* xr = x + row * 768;
  const int t = threadIdx.x;
  float v0 = xr[t], v1 = xr[t+256], v2 = xr[t+512];
  float s = v0+v1+v2;
  float q = v0*v0 + v1*v1 + v2*v2;
  #pragma unroll
  for (int o=1;o<64;o<<=1){ s += __shfl_xor(s,o); q += __shfl_xor(q,o); }
  __shared__ float rs_[4], rq_[4];
  if ((t & 63) == 0){ rs_[t>>6] = s; rq_[t>>6] = q; }
  __syncthreads();
  s = rs_[0]+rs_[1]+rs_[2]+rs_[3];
  q = rq_[0]+rq_[1]+rq_[2]+rq_[3];
  const float m = s * (1.f/768.f);
  const float var = q * (1.f/768.f) - m*m;
  const float rstd = rsqrtf(var + 1e-6f);
  u16* yr = y + row * 768;
  yr[t]     = f2bf((v0-m)*rstd*g[t]     + bta[t]);
  yr[t+256] = f2bf((v1-m)*rstd*g[t+256] + bta[t+256]);
  yr[t+512] = f2bf((v2-m)*rstd*g[t+512] + bta[t+512]);
}

// ---------------- transpose+cast: out[n][k] = bf16(in[k*ld + n]), k<768 ----
__global__ __launch_bounds__(256) void tcast(const float* __restrict__ in,
    int ld, int ncnt, u16* __restrict__ out)
{
  __shared__ float tile[32][33];
  const int tx = threadIdx.x & 31, ty = threadIdx.x >> 5;
  const int n0 = blockIdx.x * 32, k0 = blockIdx.y * 32;
  #pragma unroll
  for (int i=0;i<4;i++){
    int k = k0 + ty + 8*i, n = n0 + tx;
    tile[ty+8*i][tx] = (n < ncnt) ? in[(size_t)k*ld + n] : 0.f;
  }
  __syncthreads();
  #pragma unroll
  for (int i=0;i<4;i++){
    int n = n0 + ty + 8*i, k = k0 + tx;
    if (n < ncnt) out[(size_t)n*768 + k] = f2bf(tile[tx][ty+8*i]);
  }
}

__global__ void pack_bsa(const float* __restrict__ bs, const float* __restrict__ ba,
                         float* __restrict__ bsa)
{
  int t = threadIdx.x;
  bsa[t] = (t < 144) ? bs[t] : ((t < 216) ? ba[t-144] : 0.f);
}

// ---------------- bf16 MFMA GEMM: C[M,N] = A[M,K] * Bt[N,K]^T + bias -------
// 128x128 tile, BK=32, 256 threads (4 waves, 2x2 wave grid, 64x64 per wave).
// 1-D grid + bijective XCD swizzle (nwg % 8 == 0 for all call sites).
// LDS chunk-XOR swizzle (c' = c ^ ((row>>1)&3)) applied on the global SOURCE
// address (global_load_lds writes lane-linear) and inverted on the ds_read
// address -> conflict-free b128 reads.
// OUT_KIND: 0 = bf16 out, 1 = f32 out, 2 = f32 out + residual
template<int OUT_KIND>
__global__ __launch_bounds__(256) void gemm_bt(
    const u16* __restrict__ A, const u16* __restrict__ Bt,
    const float* __restrict__ bias, const float* __restrict__ res,
    void* __restrict__ Cout, int M, int N, int K, int nbx)
{
  __shared__ u16 sA[128*32];
  __shared__ u16 sB[128*32];
  const int nwg = gridDim.x;
  const int q8 = nwg >> 3;
  const int bid = blockIdx.x;
  const int swz = (bid & 7) * q8 + (bid >> 3);   // XCD-chunked, row-panel-major
  const int bx = swz % nbx, by = swz / nbx;
  const int m0 = by * 128, n0 = bx * 128;
  const int t = threadIdx.x;
  const int w = t >> 6, lane = t & 63;
  const int wr = w >> 1, wc = w & 1;

  f32x4 acc[4][4];
  #pragma unroll
  for (int mi=0;mi<4;mi++)
    #pragma unroll
    for (int ni=0;ni<4;ni++)
      acc[mi][ni] = (f32x4){0.f,0.f,0.f,0.f};

  // staging: wave w covers rows [w*32, w*32+32); lane l -> row w*32+i*16+(l>>2),
  // source k-chunk pre-swizzled: csrc = (l&3) ^ ((l>>3)&3)
  const int rST = w*32 + (lane>>2);
  const int cSRC = (((lane&3) ^ ((lane>>3)&3))) * 8;
  const u16* gA = A + (size_t)(m0 + rST)*K + cSRC;
  const u16* gB = Bt + (size_t)(n0 + rST)*K + cSRC;
  u16* lA = sA + (w*32)*32;   // wave-uniform LDS base
  u16* lB = sB + (w*32)*32;
  // read-side: chunk kc at row R lives in slot kc ^ ((R>>1)&3); (R>>1)&3
  // reduces to ((lane&15)>>1)&3 (row bases are multiples of 16)
  const int kc = lane >> 4;
  const int koff = (kc ^ (((lane&15)>>1)&3)) * 8;

  for (int k0 = 0; k0 < K; k0 += 32) {
    __syncthreads();
    __builtin_amdgcn_global_load_lds(GLOBAL_AS(gA),                LDS_AS(lA),          16, 0, 0);
    __builtin_amdgcn_global_load_lds(GLOBAL_AS(gA + 16*(size_t)K), LDS_AS(lA + 16*32),  16, 0, 0);
    __builtin_amdgcn_global_load_lds(GLOBAL_AS(gB),                LDS_AS(lB),          16, 0, 0);
    __builtin_amdgcn_global_load_lds(GLOBAL_AS(gB + 16*(size_t)K), LDS_AS(lB + 16*32),  16, 0, 0);
    gA += 32; gB += 32;
    __syncthreads();

    short8 af[4], bfr[4];
    #pragma unroll
    for (int mi=0;mi<4;mi++)
      af[mi] = *(const short8*)&sA[(wr*64 + mi*16 + (lane&15))*32 + koff];
    #pragma unroll
    for (int ni=0;ni<4;ni++)
      bfr[ni] = *(const short8*)&sB[(wc*64 + ni*16 + (lane&15))*32 + koff];
    #pragma unroll
    for (int mi=0;mi<4;mi++)
      #pragma unroll
      for (int ni=0;ni<4;ni++)
        acc[mi][ni] = __builtin_amdgcn_mfma_f32_16x16x32_bf16(af[mi], bfr[ni], acc[mi][ni], 0, 0, 0);
  }

  #pragma unroll
  for (int ni=0;ni<4;ni++){
    const int col = n0 + wc*64 + ni*16 + (lane&15);
    const float bc = bias[col];
    #pragma unroll
    for (int mi=0;mi<4;mi++){
      const int row0 = m0 + wr*64 + mi*16 + (lane>>4)*4;
      #pragma unroll
      for (int r=0;r<4;r++){
        float v = acc[mi][ni][r] + bc;
        size_t off = (size_t)(row0+r)*N + col;
        if constexpr (OUT_KIND == 0)      ((u16*)Cout)[off] = f2bf(v);
        else if constexpr (OUT_KIND == 1) ((float*)Cout)[off] = v;
        else                              ((float*)Cout)[off] = v + res[off];
      }
    }
  }
}

// ---------------- deformable sampling + attention-weighted accumulate ------
// 192 threads/block, 2 queries/block. 96 threads per query; each thread owns
// 8 contiguous bf16 columns (dwordx4 gathers). Branchless: invalid corners
// have wgt==0 and clamped (safe) indices.
#define NQ_ 4096
#define LV_ 21504

__global__ __launch_bounds__(192) void sample_kernel(
    const float* __restrict__ offattn, const float* __restrict__ refp,
    const u16* __restrict__ value, u16* __restrict__ accb)
{
  __shared__ float s_w[2][4][72];
  __shared__ int   s_idx[2][4][72];
  __shared__ float s_at[2][72];
  const int t = threadIdx.x;

  if (t < 144) {
    const int qi = t / 72, s = t % 72;
    const int bq = blockIdx.x*2 + qi;
    const float* row = offattn + (size_t)bq * 256;
    const int j = s % 12, l = j >> 2;
    const float Wf = (l==0) ? 128.f : ((l==1) ? 64.f : 32.f);
    const int   Wi = (l==0) ? 128   : ((l==1) ? 64   : 32);
    const int   st = (l==0) ? 0     : ((l==1) ? 16384 : 20480);
    const float rx = refp[((size_t)bq*3 + l)*2 + 0];
    const float ry = refp[((size_t)bq*3 + l)*2 + 1];
    const float px = rx*Wf + row[2*s]   - 0.5f;
    const float py = ry*Wf + row[2*s+1] - 0.5f;
    const float x0f = floorf(px), y0f = floorf(py);
    const int x0 = (int)x0f, y0 = (int)y0f;
    const float fx = px - x0f, fy = py - y0f;
    #pragma unroll
    for (int c=0;c<4;c++){
      const int dx = c & 1, dy = c >> 1;
      const int ix = x0 + dx, iy = y0 + dy;
      const float wgt = (dx ? fx : 1.f-fx) * (dy ? fy : 1.f-fy);
      const bool ok = (ix >= 0) && (ix < Wi) && (iy >= 0) && (iy < Wi);
      const int cx = min(max(ix,0),Wi-1), cy = min(max(iy,0),Wi-1);
      s_w[qi][c][s]   = ok ? wgt : 0.f;
      s_idx[qi][c][s] = st + cy*Wi + cx;
    }
  } else if (t < 156) {
    const int u = t - 144, qi = u / 6, h = u % 6;
    const int bq = blockIdx.x*2 + qi;
    const float* lg = offattn + (size_t)bq * 256 + 144 + h*12;
    float m = lg[0];
    #pragma unroll
    for (int j2=1;j2<12;j2++) m = fmaxf(m, lg[j2]);
    float e[12]; float sum = 0.f;
    #pragma unroll
    for (int j2=0;j2<12;j2++){ e[j2] = __expf(lg[j2]-m); sum += e[j2]; }
    const float inv = 1.f/sum;
    #pragma unroll
    for (int j2=0;j2<12;j2++) s_at[qi][h*12+j2] = e[j2]*inv;
  }
  __syncthreads();

  const int qi = t / 96, tt = t % 96;
  const int bq = blockIdx.x*2 + qi;
  const int b = bq >> 12;
  const int cb = tt * 8;          // u16 column base
  const int h = cb >> 7;          // head
  const u16* vb = value + (size_t)b * LV_ * 768;

  float ax[8];
  #pragma unroll
  for (int k=0;k<8;k++) ax[k] = 0.f;

  #pragma unroll 2
  for (int j2=0;j2<12;j2++){
    const int s = h*12 + j2;
    const float at = s_at[qi][s];
    float sx[8];
    #pragma unroll
    for (int k=0;k<8;k++) sx[k] = 0.f;
    #pragma unroll
    for (int c=0;c<4;c++){
      const float wgt = s_w[qi][c][s];
      const u32x4 u = *(const u32x4*)(vb + (size_t)s_idx[qi][c][s]*768 + cb);
      sx[0] += wgt * lo16(u[0]); sx[1] += wgt * hi16(u[0]);
      sx[2] += wgt * lo16(u[1]); sx[3] += wgt * hi16(u[1]);
      sx[4] += wgt * lo16(u[2]); sx[5] += wgt * hi16(u[2]);
      sx[6] += wgt * lo16(u[3]); sx[7] += wgt * hi16(u[3]);
    }
    #pragma unroll
    for (int k=0;k<8;k++) ax[k] += at * sx[k];
  }

  u16* ob = accb + (size_t)bq * 768 + cb;
  u32x4 o;
  #pragma unroll
  for (int k=0;k<4;k++)
    o[k] = ((uint32_t)f2bf(ax[2*k+1]) << 16) | (uint32_t)f2bf(ax[2*k]);
  *(u32x4*)ob = o;
}

// ---------------------------------------------------------------------------
extern "C" void kernel_launch(void* const* d_in, const int* in_sizes, int n_in,
                              void* d_out, int out_size, void* d_ws, size_t ws_size,
                              hipStream_t stream) {
  (void)in_sizes; (void)n_in; (void)out_size; (void)ws_size;
  const float* query = (const float*)d_in[0];
  const float* refp  = (const float*)d_in[1];
  const float* feat  = (const float*)d_in[2];
  const float* qn_g  = (const float*)d_in[3];
  const float* qn_b  = (const float*)d_in[4];
  const float* fn_g  = (const float*)d_in[5];
  const float* fn_b  = (const float*)d_in[6];
  const float* Wv    = (const float*)d_in[7];
  const float* bv    = (const float*)d_in[8];
  const float* Ws    = (const float*)d_in[9];
  const float* bs    = (const float*)d_in[10];
  const float* Wa    = (const float*)d_in[11];
  const float* ba    = (const float*)d_in[12];
  const float* Wo    = (const float*)d_in[13];
  const float* bo    = (const float*)d_in[14];
  float* out = (float*)d_out;

  // workspace layout (bytes)
  constexpr size_t SZ_FLN  = (size_t)43008*768*2;  // 66,060,288
  constexpr size_t SZ_QLN  = (size_t)8192*768*2;   // 12,582,912
  constexpr size_t SZ_W    = (size_t)768*768*2;    // 1,179,648
  constexpr size_t SZ_WSAT = (size_t)256*768*2;    // 393,216
  char* ws = (char*)d_ws;
  u16*  fln   = (u16*)(ws);
  u16*  value = (u16*)(ws + SZ_FLN);
  u16*  qln   = (u16*)(ws + 2*SZ_FLN);
  u16*  Wvt   = (u16*)(ws + 2*SZ_FLN + SZ_QLN);
  u16*  Wot   = (u16*)(ws + 2*SZ_FLN + SZ_QLN + SZ_W);
  u16*  Wsat  = (u16*)(ws + 2*SZ_FLN + SZ_QLN + 2*SZ_W);
  float* bsa  = (float*)(ws + 2*SZ_FLN + SZ_QLN + 2*SZ_W + SZ_WSAT);
  float* offattn = (float*)fln;   // alias: fln dead after value GEMM
  u16*   accb    = qln;           // alias: qln dead after off/attn GEMM

  // 1) LayerNorms -> bf16
  ln_cast<<<8192, 256, 0, stream>>>(query, qn_g, qn_b, qln);
  ln_cast<<<43008, 256, 0, stream>>>(feat, fn_g, fn_b, fln);

  // 2) weight pre-transpose/cast (Bt layouts [N][K])
  tcast<<<dim3(24,24), 256, 0, stream>>>(Wv, 768, 768, Wvt);
  tcast<<<dim3(24,24), 256, 0, stream>>>(Wo, 768, 768, Wot);
  hipMemsetAsync(Wsat, 0, SZ_WSAT, stream);
  tcast<<<dim3(5,24), 256, 0, stream>>>(Ws, 144, 144, Wsat);
  tcast<<<dim3(3,24), 256, 0, stream>>>(Wa, 72, 72, Wsat + (size_t)144*768);
  pack_bsa<<<1, 256, 0, stream>>>(bs, ba, bsa);

  // 3) value = LN(feat) @ Wv + bv  -> bf16 [2*21504, 768]   (2016 blocks)
  gemm_bt<0><<<2016, 256, 0, stream>>>(fln, Wvt, bv, nullptr, value, 43008, 768, 768, 6);

  // 4) off/attn logits = LN(query) @ [Ws|Wa] + [bs|ba] -> f32 [8192, 256]
  gemm_bt<1><<<128, 256, 0, stream>>>(qln, Wsat, bsa, nullptr, offattn, 8192, 256, 768, 2);

  // 5) deformable sampling + softmax-weighted accumulation -> bf16 [8192, 768]
  sample_kernel<<<4096, 192, 0, stream>>>(offattn, refp, value, accb);

  // 6) out = acc @ Wo + bo + query -> f32
  gemm_bt<2><<<384, 256, 0, stream>>>(accb, Wot, bo, query, out, 8192, 768, 768, 6);
}

// Round 4
// 240.990 us; speedup vs baseline: 1.4232x; 1.0374x over previous
//
#include <hip/hip_runtime.h>
#include <cstdint>
#include <cstddef>

typedef unsigned short u16;
typedef __attribute__((ext_vector_type(8))) short short8;
typedef __attribute__((ext_vector_type(4))) float f32x4;
typedef __attribute__((ext_vector_type(4))) unsigned int u32x4;

#define GLOBAL_AS(p) ((const __attribute__((address_space(1))) void*)(p))
#define LDS_AS(p)    ((__attribute__((address_space(3))) void*)(p))

__device__ __forceinline__ float bf2f(u16 u){
  union { uint32_t u; float f; } c; c.u = ((uint32_t)u) << 16; return c.f;
}
__device__ __forceinline__ float lo16(uint32_t u){
  union { uint32_t u; float f; } c; c.u = u << 16; return c.f;
}
__device__ __forceinline__ float hi16(uint32_t u){
  union { uint32_t u; float f; } c; c.u = u & 0xffff0000u; return c.f;
}
__device__ __forceinline__ u16 f2bf(float f){
  union { float f; uint32_t u; } c; c.f = f;
  uint32_t r = c.u + 0x7fffu + ((c.u >> 16) & 1u);
  return (u16)(r >> 16);
}

// ---------------- LayerNorm + cast to bf16 (one block per 768-elem row) ----
__global__ __launch_bounds__(256) void ln_cast(const float* __restrict__ x,
    const float* __restrict__ g, const float* __restrict__ bta,
    u16* __restrict__ y)
{
  const size_t row = blockIdx.x;
  const float* xr = x + row * 768;
  const int t = threadIdx.x;
  float v0 = xr[t], v1 = xr[t+256], v2 = xr[t+512];
  float s = v0+v1+v2;
  float q = v0*v0 + v1*v1 + v2*v2;
  #pragma unroll
  for (int o=1;o<64;o<<=1){ s += __shfl_xor(s,o); q += __shfl_xor(q,o); }
  __shared__ float rs_[4], rq_[4];
  if ((t & 63) == 0){ rs_[t>>6] = s; rq_[t>>6] = q; }
  __syncthreads();
  s = rs_[0]+rs_[1]+rs_[2]+rs_[3];
  q = rq_[0]+rq_[1]+rq_[2]+rq_[3];
  const float m = s * (1.f/768.f);
  const float var = q * (1.f/768.f) - m*m;
  const float rstd = rsqrtf(var + 1e-6f);
  u16* yr = y + row * 768;
  yr[t]     = f2bf((v0-m)*rstd*g[t]     + bta[t]);
  yr[t+256] = f2bf((v1-m)*rstd*g[t+256] + bta[t+256]);
  yr[t+512] = f2bf((v2-m)*rstd*g[t+512] + bta[t+512]);
}

// ---------------- transpose+cast: out[n][k] = bf16(in[k*ld + n]), k<768 ----
__global__ __launch_bounds__(256) void tcast(const float* __restrict__ in,
    int ld, int ncnt, u16* __restrict__ out)
{
  __shared__ float tile[32][33];
  const int tx = threadIdx.x & 31, ty = threadIdx.x >> 5;
  const int n0 = blockIdx.x * 32, k0 = blockIdx.y * 32;
  #pragma unroll
  for (int i=0;i<4;i++){
    int k = k0 + ty + 8*i, n = n0 + tx;
    tile[ty+8*i][tx] = (n < ncnt) ? in[(size_t)k*ld + n] : 0.f;
  }
  __syncthreads();
  #pragma unroll
  for (int i=0;i<4;i++){
    int n = n0 + ty + 8*i, k = k0 + tx;
    if (n < ncnt) out[(size_t)n*768 + k] = f2bf(tile[tx][ty+8*i]);
  }
}

__global__ void pack_bsa(const float* __restrict__ bs, const float* __restrict__ ba,
                         float* __restrict__ bsa)
{
  int t = threadIdx.x;
  bsa[t] = (t < 144) ? bs[t] : ((t < 216) ? ba[t-144] : 0.f);
}

// ================== deep-pipelined 256x256 MFMA GEMM (bf16 out) ============
// BK=64, 512 threads = 8 waves (2M x 4N), per-wave C = 128x64.
// LDS: 2 dbuf x (A 256x64 + B 256x64) bf16 = 128 KiB -> 1 block/CU, 2 waves/SIMD.
// Per K-tile: 2 phases. Even phase: ds_read A-half(mh0)+all-B frags, stage
// A(k+1) -> other buf, 32 MFMA. Odd: ds_read A-half(mh1) (B in regs), stage
// B(k+2) -> current buf (B region dead after even phase), 32 MFMA, vmcnt(4)
// (tile k+1 landed; B(k+2) stays in flight), barrier. Raw s_barrier +
// lgkmcnt(0); vmcnt never 0 in loop. Chunk-XOR LDS swizzle slot=c^(row&7),
// applied on the pre-swizzled global source (global_load_lds is lane-linear).
__global__ __launch_bounds__(512, 2) void gemm8(
    const u16* __restrict__ A, const u16* __restrict__ Bt,
    const float* __restrict__ bias,
    u16* __restrict__ Cout, int M, int N, int K, int nbx)
{
  __shared__ u16 lds[2][2][256*64];
  const int nwg = gridDim.x;                       // multiple of 8
  const int bid = blockIdx.x;
  const int swz = (bid & 7) * (nwg >> 3) + (bid >> 3);
  const int bx = swz % nbx, by = swz / nbx;
  const int m0 = by*256, n0 = bx*256;
  const int t = threadIdx.x, w = t >> 6, lane = t & 63;
  const int wm = w >> 2, wn = w & 3;
  const int NT = K >> 6;
  const int lr = lane & 15, r7 = lane & 7;

  // staging: per half-tile (128 rows x 64 cols), 2 loads/thread.
  // wave-uniform LDS base + lane*16 -> lane l lands row (w*8 + l>>3)+{0,64},
  // chunk l&7. Source chunk pre-swizzled: c_src = (l&7) ^ ((l>>3)&7).
  const int stRow  = (w << 3) + (lane >> 3);
  const int stColU = (((lane & 7) ^ ((lane >> 3) & 7)) << 3);

  f32x4 acc[8][4];
  #pragma unroll
  for (int j=0;j<8;j++)
    #pragma unroll
    for (int ni=0;ni<4;ni++)
      acc[j][ni] = (f32x4){0.f,0.f,0.f,0.f};

  #define STAGE(op, half, kt, buf, G, gbase)                                   \
    { const u16* gsrc_ = (G) + (size_t)((gbase) + (half)*128 + stRow)*K        \
                              + (kt)*64 + stColU;                              \
      u16* l_ = &lds[buf][op][((half)*128 + (w<<3))*64];                       \
      __builtin_amdgcn_global_load_lds(GLOBAL_AS(gsrc_), LDS_AS(l_), 16,0,0);  \
      __builtin_amdgcn_global_load_lds(GLOBAL_AS(gsrc_ + (size_t)64*K),        \
                                       LDS_AS(l_ + 64*64), 16,0,0); }

  // prologue: A(0),B(0) -> buf0; B(1) -> buf1.  (12 loads; wait oldest 8)
  STAGE(0,0,0,0, A,  m0); STAGE(0,1,0,0, A,  m0);
  STAGE(1,0,0,0, Bt, n0); STAGE(1,1,0,0, Bt, n0);
  STAGE(1,0,1,1, Bt, n0); STAGE(1,1,1,1, Bt, n0);
  asm volatile("s_waitcnt vmcnt(4)" ::: "memory");
  __builtin_amdgcn_s_barrier();

  short8 bfrag[4][2];
  const int slot0 = ((0 + (lane>>4)) ^ r7) * 8;     // kk=0 chunk slot (u16)
  const int slot1 = ((4 + (lane>>4)) ^ r7) * 8;     // kk=1

  for (int kt = 0; kt < NT; ++kt) {
    const int buf = kt & 1;
    const u16* lA = &lds[buf][0][(wm*128 + lr)*64];
    const u16* lB = &lds[buf][1][(wn*64  + lr)*64];

    // ---------------- even phase (mh = 0) ----------------
    short8 af[4][2];
    #pragma unroll
    for (int mi=0;mi<4;mi++){
      af[mi][0] = *(const short8*)(lA + mi*16*64 + slot0);
      af[mi][1] = *(const short8*)(lA + mi*16*64 + slot1);
    }
    #pragma unroll
    for (int ni=0;ni<4;ni++){
      bfrag[ni][0] = *(const short8*)(lB + ni*16*64 + slot0);
      bfrag[ni][1] = *(const short8*)(lB + ni*16*64 + slot1);
    }
    { const int ktn = (kt+1 < NT) ? kt+1 : NT-1;    // A(k+1) -> other buf
      const int b2 = (kt+1) & 1;
      STAGE(0,0,ktn,b2, A, m0); STAGE(0,1,ktn,b2, A, m0); }
    __builtin_amdgcn_s_barrier();
    asm volatile("s_waitcnt lgkmcnt(0)" ::: "memory");
    __builtin_amdgcn_sched_barrier(0);
    __builtin_amdgcn_s_setprio(1);
    #pragma unroll
    for (int mi=0;mi<4;mi++)
      #pragma unroll
      for (int ni=0;ni<4;ni++){
        acc[mi][ni] = __builtin_amdgcn_mfma_f32_16x16x32_bf16(af[mi][0], bfrag[ni][0], acc[mi][ni], 0,0,0);
        acc[mi][ni] = __builtin_amdgcn_mfma_f32_16x16x32_bf16(af[mi][1], bfrag[ni][1], acc[mi][ni], 0,0,0);
      }
    __builtin_amdgcn_s_setprio(0);
    __builtin_amdgcn_s_barrier();

    // ---------------- odd phase (mh = 1) ----------------
    #pragma unroll
    for (int mi=0;mi<4;mi++){
      af[mi][0] = *(const short8*)(lA + (64 + mi*16)*64 + slot0);
      af[mi][1] = *(const short8*)(lA + (64 + mi*16)*64 + slot1);
    }
    { const int ktn = (kt+2 < NT) ? kt+2 : NT-1;    // B(k+2) -> current buf
      STAGE(1,0,ktn,buf, Bt, n0); STAGE(1,1,ktn,buf, Bt, n0); }
    __builtin_amdgcn_s_barrier();
    asm volatile("s_waitcnt lgkmcnt(0)" ::: "memory");
    __builtin_amdgcn_sched_barrier(0);
    __builtin_amdgcn_s_setprio(1);
    #pragma unroll
    for (int mi=0;mi<4;mi++)
      #pragma unroll
      for (int ni=0;ni<4;ni++){
        acc[4+mi][ni] = __builtin_amdgcn_mfma_f32_16x16x32_bf16(af[mi][0], bfrag[ni][0], acc[4+mi][ni], 0,0,0);
        acc[4+mi][ni] = __builtin_amdgcn_mfma_f32_16x16x32_bf16(af[mi][1], bfrag[ni][1], acc[4+mi][ni], 0,0,0);
      }
    __builtin_amdgcn_s_setprio(0);
    asm volatile("s_waitcnt vmcnt(4)" ::: "memory");
    __builtin_amdgcn_s_barrier();
  }
  #undef STAGE

  // epilogue: D frag col=lane&15, row=(lane>>4)*4+reg
  #pragma unroll
  for (int ni=0;ni<4;ni++){
    const int col = n0 + wn*64 + ni*16 + lr;
    const float bc = bias[col];
    #pragma unroll
    for (int j=0;j<8;j++){
      const int row0 = m0 + wm*128 + (j>>2)*64 + (j&3)*16 + (lane>>4)*4;
      #pragma unroll
      for (int r=0;r<4;r++)
        Cout[(size_t)(row0+r)*N + col] = f2bf(acc[j][ni][r] + bc);
    }
  }
}

// ---------------- 128x128 MFMA GEMM (kept for small GEMMs) -----------------
// OUT_KIND: 1 = f32 out, 2 = f32 out + residual
template<int OUT_KIND>
__global__ __launch_bounds__(256) void gemm_bt(
    const u16* __restrict__ A, const u16* __restrict__ Bt,
    const float* __restrict__ bias, const float* __restrict__ res,
    void* __restrict__ Cout, int M, int N, int K, int nbx)
{
  __shared__ u16 sA[128*32];
  __shared__ u16 sB[128*32];
  const int nwg = gridDim.x;
  const int q8 = nwg >> 3;
  const int bid = blockIdx.x;
  const int swz = (bid & 7) * q8 + (bid >> 3);
  const int bx = swz % nbx, by = swz / nbx;
  const int m0 = by * 128, n0 = bx * 128;
  const int t = threadIdx.x;
  const int w = t >> 6, lane = t & 63;
  const int wr = w >> 1, wc = w & 1;

  f32x4 acc[4][4];
  #pragma unroll
  for (int mi=0;mi<4;mi++)
    #pragma unroll
    for (int ni=0;ni<4;ni++)
      acc[mi][ni] = (f32x4){0.f,0.f,0.f,0.f};

  const int rST = w*32 + (lane>>2);
  const int cSRC = (((lane&3) ^ ((lane>>3)&3))) * 8;
  const u16* gA = A + (size_t)(m0 + rST)*K + cSRC;
  const u16* gB = Bt + (size_t)(n0 + rST)*K + cSRC;
  u16* lA = sA + (w*32)*32;
  u16* lB = sB + (w*32)*32;
  const int kc = lane >> 4;
  const int koff = (kc ^ (((lane&15)>>1)&3)) * 8;

  for (int k0 = 0; k0 < K; k0 += 32) {
    __syncthreads();
    __builtin_amdgcn_global_load_lds(GLOBAL_AS(gA),                LDS_AS(lA),          16, 0, 0);
    __builtin_amdgcn_global_load_lds(GLOBAL_AS(gA + 16*(size_t)K), LDS_AS(lA + 16*32),  16, 0, 0);
    __builtin_amdgcn_global_load_lds(GLOBAL_AS(gB),                LDS_AS(lB),          16, 0, 0);
    __builtin_amdgcn_global_load_lds(GLOBAL_AS(gB + 16*(size_t)K), LDS_AS(lB + 16*32),  16, 0, 0);
    gA += 32; gB += 32;
    __syncthreads();

    short8 af[4], bfr[4];
    #pragma unroll
    for (int mi=0;mi<4;mi++)
      af[mi] = *(const short8*)&sA[(wr*64 + mi*16 + (lane&15))*32 + koff];
    #pragma unroll
    for (int ni=0;ni<4;ni++)
      bfr[ni] = *(const short8*)&sB[(wc*64 + ni*16 + (lane&15))*32 + koff];
    #pragma unroll
    for (int mi=0;mi<4;mi++)
      #pragma unroll
      for (int ni=0;ni<4;ni++)
        acc[mi][ni] = __builtin_amdgcn_mfma_f32_16x16x32_bf16(af[mi], bfr[ni], acc[mi][ni], 0, 0, 0);
  }

  #pragma unroll
  for (int ni=0;ni<4;ni++){
    const int col = n0 + wc*64 + ni*16 + (lane&15);
    const float bc = bias[col];
    #pragma unroll
    for (int mi=0;mi<4;mi++){
      const int row0 = m0 + wr*64 + mi*16 + (lane>>4)*4;
      #pragma unroll
      for (int r=0;r<4;r++){
        float v = acc[mi][ni][r] + bc;
        size_t off = (size_t)(row0+r)*N + col;
        if constexpr (OUT_KIND == 1) ((float*)Cout)[off] = v;
        else                         ((float*)Cout)[off] = v + res[off];
      }
    }
  }
}

// ---------------- deformable sampling + attention-weighted accumulate ------
#define NQ_ 4096
#define LV_ 21504

__global__ __launch_bounds__(192) void sample_kernel(
    const float* __restrict__ offattn, const float* __restrict__ refp,
    const u16* __restrict__ value, u16* __restrict__ accb)
{
  __shared__ float s_w[2][4][72];
  __shared__ int   s_idx[2][4][72];
  __shared__ float s_at[2][72];
  const int t = threadIdx.x;

  if (t < 144) {
    const int qi = t / 72, s = t % 72;
    const int bq = blockIdx.x*2 + qi;
    const float* row = offattn + (size_t)bq * 256;
    const int j = s % 12, l = j >> 2;
    const float Wf = (l==0) ? 128.f : ((l==1) ? 64.f : 32.f);
    const int   Wi = (l==0) ? 128   : ((l==1) ? 64   : 32);
    const int   st = (l==0) ? 0     : ((l==1) ? 16384 : 20480);
    const float rx = refp[((size_t)bq*3 + l)*2 + 0];
    const float ry = refp[((size_t)bq*3 + l)*2 + 1];
    const float px = rx*Wf + row[2*s]   - 0.5f;
    const float py = ry*Wf + row[2*s+1] - 0.5f;
    const float x0f = floorf(px), y0f = floorf(py);
    const int x0 = (int)x0f, y0 = (int)y0f;
    const float fx = px - x0f, fy = py - y0f;
    #pragma unroll
    for (int c=0;c<4;c++){
      const int dx = c & 1, dy = c >> 1;
      const int ix = x0 + dx, iy = y0 + dy;
      const float wgt = (dx ? fx : 1.f-fx) * (dy ? fy : 1.f-fy);
      const bool ok = (ix >= 0) && (ix < Wi) && (iy >= 0) && (iy < Wi);
      const int cx = min(max(ix,0),Wi-1), cy = min(max(iy,0),Wi-1);
      s_w[qi][c][s]   = ok ? wgt : 0.f;
      s_idx[qi][c][s] = st + cy*Wi + cx;
    }
  } else if (t < 156) {
    const int u = t - 144, qi = u / 6, h = u % 6;
    const int bq = blockIdx.x*2 + qi;
    const float* lg = offattn + (size_t)bq * 256 + 144 + h*12;
    float m = lg[0];
    #pragma unroll
    for (int j2=1;j2<12;j2++) m = fmaxf(m, lg[j2]);
    float e[12]; float sum = 0.f;
    #pragma unroll
    for (int j2=0;j2<12;j2++){ e[j2] = __expf(lg[j2]-m); sum += e[j2]; }
    const float inv = 1.f/sum;
    #pragma unroll
    for (int j2=0;j2<12;j2++) s_at[qi][h*12+j2] = e[j2]*inv;
  }
  __syncthreads();

  const int qi = t / 96, tt = t % 96;
  const int bq = blockIdx.x*2 + qi;
  const int b = bq >> 12;
  const int cb = tt * 8;
  const int h = cb >> 7;
  const u16* vb = value + (size_t)b * LV_ * 768;

  float ax[8];
  #pragma unroll
  for (int k=0;k<8;k++) ax[k] = 0.f;

  #pragma unroll 2
  for (int j2=0;j2<12;j2++){
    const int s = h*12 + j2;
    const float at = s_at[qi][s];
    float sx[8];
    #pragma unroll
    for (int k=0;k<8;k++) sx[k] = 0.f;
    #pragma unroll
    for (int c=0;c<4;c++){
      const float wgt = s_w[qi][c][s];
      const u32x4 u = *(const u32x4*)(vb + (size_t)s_idx[qi][c][s]*768 + cb);
      sx[0] += wgt * lo16(u[0]); sx[1] += wgt * hi16(u[0]);
      sx[2] += wgt * lo16(u[1]); sx[3] += wgt * hi16(u[1]);
      sx[4] += wgt * lo16(u[2]); sx[5] += wgt * hi16(u[2]);
      sx[6] += wgt * lo16(u[3]); sx[7] += wgt * hi16(u[3]);
    }
    #pragma unroll
    for (int k=0;k<8;k++) ax[k] += at * sx[k];
  }

  u16* ob = accb + (size_t)bq * 768 + cb;
  u32x4 o;
  #pragma unroll
  for (int k=0;k<4;k++)
    o[k] = ((uint32_t)f2bf(ax[2*k+1]) << 16) | (uint32_t)f2bf(ax[2*k]);
  *(u32x4*)ob = o;
}

// ---------------------------------------------------------------------------
extern "C" void kernel_launch(void* const* d_in, const int* in_sizes, int n_in,
                              void* d_out, int out_size, void* d_ws, size_t ws_size,
                              hipStream_t stream) {
  (void)in_sizes; (void)n_in; (void)out_size; (void)ws_size;
  const float* query = (const float*)d_in[0];
  const float* refp  = (const float*)d_in[1];
  const float* feat  = (const float*)d_in[2];
  const float* qn_g  = (const float*)d_in[3];
  const float* qn_b  = (const float*)d_in[4];
  const float* fn_g  = (const float*)d_in[5];
  const float* fn_b  = (const float*)d_in[6];
  const float* Wv    = (const float*)d_in[7];
  const float* bv    = (const float*)d_in[8];
  const float* Ws    = (const float*)d_in[9];
  const float* bs    = (const float*)d_in[10];
  const float* Wa    = (const float*)d_in[11];
  const float* ba    = (const float*)d_in[12];
  const float* Wo    = (const float*)d_in[13];
  const float* bo    = (const float*)d_in[14];
  float* out = (float*)d_out;

  constexpr size_t SZ_FLN  = (size_t)43008*768*2;
  constexpr size_t SZ_QLN  = (size_t)8192*768*2;
  constexpr size_t SZ_W    = (size_t)768*768*2;
  constexpr size_t SZ_WSAT = (size_t)256*768*2;
  char* ws = (char*)d_ws;
  u16*  fln   = (u16*)(ws);
  u16*  value = (u16*)(ws + SZ_FLN);
  u16*  qln   = (u16*)(ws + 2*SZ_FLN);
  u16*  Wvt   = (u16*)(ws + 2*SZ_FLN + SZ_QLN);
  u16*  Wot   = (u16*)(ws + 2*SZ_FLN + SZ_QLN + SZ_W);
  u16*  Wsat  = (u16*)(ws + 2*SZ_FLN + SZ_QLN + 2*SZ_W);
  float* bsa  = (float*)(ws + 2*SZ_FLN + SZ_QLN + 2*SZ_W + SZ_WSAT);
  float* offattn = (float*)fln;
  u16*   accb    = qln;

  // 1) LayerNorms -> bf16
  ln_cast<<<8192, 256, 0, stream>>>(query, qn_g, qn_b, qln);
  ln_cast<<<43008, 256, 0, stream>>>(feat, fn_g, fn_b, fln);

  // 2) weight pre-transpose/cast
  tcast<<<dim3(24,24), 256, 0, stream>>>(Wv, 768, 768, Wvt);
  tcast<<<dim3(24,24), 256, 0, stream>>>(Wo, 768, 768, Wot);
  hipMemsetAsync(Wsat, 0, SZ_WSAT, stream);
  tcast<<<dim3(5,24), 256, 0, stream>>>(Ws, 144, 144, Wsat);
  tcast<<<dim3(3,24), 256, 0, stream>>>(Wa, 72, 72, Wsat + (size_t)144*768);
  pack_bsa<<<1, 256, 0, stream>>>(bs, ba, bsa);

  // 3) value = LN(feat) @ Wv + bv -> bf16 [43008, 768]   (168x3 = 504 blocks)
  gemm8<<<504, 512, 0, stream>>>(fln, Wvt, bv, value, 43008, 768, 768, 3);

  // 4) off/attn logits = LN(query) @ [Ws|Wa] -> f32 [8192, 256]
  gemm_bt<1><<<128, 256, 0, stream>>>(qln, Wsat, bsa, nullptr, offattn, 8192, 256, 768, 2);

  // 5) deformable sampling -> bf16 [8192, 768]
  sample_kernel<<<4096, 192, 0, stream>>>(offattn, refp, value, accb);

  // 6) out = acc @ Wo + bo + query -> f32
  gemm_bt<2><<<384, 256, 0, stream>>>(accb, Wot, bo, query, out, 8192, 768, 768, 6);
}

// Round 5
// 238.323 us; speedup vs baseline: 1.4392x; 1.0112x over previous
//
#include <hip/hip_runtime.h>
#include <cstdint>
#include <cstddef>

typedef unsigned short u16;
typedef __attribute__((ext_vector_type(8))) short short8;
typedef __attribute__((ext_vector_type(4))) float f32x4;
typedef __attribute__((ext_vector_type(4))) unsigned int u32x4;

#define GLOBAL_AS(p) ((const __attribute__((address_space(1))) void*)(p))
#define LDS_AS(p)    ((__attribute__((address_space(3))) void*)(p))

__device__ __forceinline__ float bf2f(u16 u){
  union { uint32_t u; float f; } c; c.u = ((uint32_t)u) << 16; return c.f;
}
__device__ __forceinline__ float lo16(uint32_t u){
  union { uint32_t u; float f; } c; c.u = u << 16; return c.f;
}
__device__ __forceinline__ float hi16(uint32_t u){
  union { uint32_t u; float f; } c; c.u = u & 0xffff0000u; return c.f;
}
__device__ __forceinline__ u16 f2bf(float f){
  union { float f; uint32_t u; } c; c.f = f;
  uint32_t r = c.u + 0x7fffu + ((c.u >> 16) & 1u);
  return (u16)(r >> 16);
}

// ---------------- LayerNorm + cast to bf16 (one block per 768-elem row) ----
__global__ __launch_bounds__(256) void ln_cast(const float* __restrict__ x,
    const float* __restrict__ g, const float* __restrict__ bta,
    u16* __restrict__ y)
{
  const size_t row = blockIdx.x;
  const float* xr = x + row * 768;
  const int t = threadIdx.x;
  float v0 = xr[t], v1 = xr[t+256], v2 = xr[t+512];
  float s = v0+v1+v2;
  float q = v0*v0 + v1*v1 + v2*v2;
  #pragma unroll
  for (int o=1;o<64;o<<=1){ s += __shfl_xor(s,o); q += __shfl_xor(q,o); }
  __shared__ float rs_[4], rq_[4];
  if ((t & 63) == 0){ rs_[t>>6] = s; rq_[t>>6] = q; }
  __syncthreads();
  s = rs_[0]+rs_[1]+rs_[2]+rs_[3];
  q = rq_[0]+rq_[1]+rq_[2]+rq_[3];
  const float m = s * (1.f/768.f);
  const float var = q * (1.f/768.f) - m*m;
  const float rstd = rsqrtf(var + 1e-6f);
  u16* yr = y + row * 768;
  yr[t]     = f2bf((v0-m)*rstd*g[t]     + bta[t]);
  yr[t+256] = f2bf((v1-m)*rstd*g[t+256] + bta[t+256]);
  yr[t+512] = f2bf((v2-m)*rstd*g[t+512] + bta[t+512]);
}

// ---------------- transpose+cast: out[n][k] = bf16(in[k*ld + n]), k<768 ----
__global__ __launch_bounds__(256) void tcast(const float* __restrict__ in,
    int ld, int ncnt, u16* __restrict__ out)
{
  __shared__ float tile[32][33];
  const int tx = threadIdx.x & 31, ty = threadIdx.x >> 5;
  const int n0 = blockIdx.x * 32, k0 = blockIdx.y * 32;
  #pragma unroll
  for (int i=0;i<4;i++){
    int k = k0 + ty + 8*i, n = n0 + tx;
    tile[ty+8*i][tx] = (n < ncnt) ? in[(size_t)k*ld + n] : 0.f;
  }
  __syncthreads();
  #pragma unroll
  for (int i=0;i<4;i++){
    int n = n0 + ty + 8*i, k = k0 + tx;
    if (n < ncnt) out[(size_t)n*768 + k] = f2bf(tile[tx][ty+8*i]);
  }
}

__global__ void pack_bsa(const float* __restrict__ bs, const float* __restrict__ ba,
                         float* __restrict__ bsa)
{
  int t = threadIdx.x;
  bsa[t] = (t < 144) ? bs[t] : ((t < 216) ? ba[t-144] : 0.f);
}

// ================== 8-phase deep-pipelined 256x256 MFMA GEMM ===============
// BK=64, 512 threads = 8 waves (2M x 4N), per-wave C = 128x64 (8 M-frags).
// Iter = 2 K-tiles (a=2i -> buf0, b=2i+1 -> buf1), 8 phases. Phase:
//   {4 ds_read_b128 A-frag-pair (+8 B at tile start) | 1-2 half-tile stage}
//   -> s_barrier -> lgkmcnt(0) -> 16 MFMA (setprio) -> [vmcnt(4) @p3,p7] -> bar
// Stage ledger (per wave, 2 loads/half-tile):
//   p0: A(b)x2 -> buf1 | p1: B0(a+2) | p2: B1(a+2) | p3: -    | vmcnt(4)
//   p4: A0(a+2)        | p5: A1(a+2) | p6: B0(b+2) | p7: B1(b+2) vmcnt(4)
// Each checkpoint lands the tile about to be read, leaves 2 half-tiles in
// flight. Every stage issues >=1 closing barrier after its dest region's last
// reader drained. Tail: stage tiles clamped to NT-1 (writes only dead regions).
__global__ __launch_bounds__(512, 2) void gemm8(
    const u16* __restrict__ A, const u16* __restrict__ Bt,
    const float* __restrict__ bias,
    u16* __restrict__ Cout, int M, int N, int K, int nbx)
{
  __shared__ u16 lds[2][2][256*64];
  const int nwg = gridDim.x;                       // multiple of 8
  const int bid = blockIdx.x;
  const int swz = (bid & 7) * (nwg >> 3) + (bid >> 3);
  const int bx = swz % nbx, by = swz / nbx;
  const int m0 = by*256, n0 = bx*256;
  const int t = threadIdx.x, w = t >> 6, lane = t & 63;
  const int wm = w >> 2, wn = w & 3;
  const int NT = K >> 6;
  const int lr = lane & 15, r7 = lane & 7;

  // staging: half-tile (128 rows x 64 cols) = 2 gload_lds(16B)/thread.
  // lane l -> row (w*8 + l>>3)+{0,64}, chunk l&7; source chunk pre-swizzled
  // c_src = (l&7) ^ ((l>>3)&7)  (LDS write is lane-linear).
  const int stRow  = (w << 3) + (lane >> 3);
  const int stColU = (((lane & 7) ^ ((lane >> 3) & 7)) << 3);

  f32x4 acc[8][4];
  #pragma unroll
  for (int j=0;j<8;j++)
    #pragma unroll
    for (int ni=0;ni<4;ni++)
      acc[j][ni] = (f32x4){0.f,0.f,0.f,0.f};

  #define STAGE(op, half, kt, buf, G, gbase)                                   \
    { const u16* gsrc_ = (G) + (size_t)((gbase) + (half)*128 + stRow)*K        \
                              + (kt)*64 + stColU;                              \
      u16* l_ = &lds[buf][op][((half)*128 + (w<<3))*64];                       \
      __builtin_amdgcn_global_load_lds(GLOBAL_AS(gsrc_), LDS_AS(l_), 16,0,0);  \
      __builtin_amdgcn_global_load_lds(GLOBAL_AS(gsrc_ + (size_t)64*K),        \
                                       LDS_AS(l_ + 64*64), 16,0,0); }

  // read-side swizzle: chunk c at row R lives in slot c ^ (R&7)
  const int slot0 = ((0 + (lane>>4)) ^ r7) * 8;     // kk=0
  const int slot1 = ((4 + (lane>>4)) ^ r7) * 8;     // kk=1

  // prologue: A(0),B(0)->buf0 (8 loads); B(1)->buf1 (4). vmcnt(4): A0,B0 landed.
  STAGE(0,0,0,0, A,  m0); STAGE(0,1,0,0, A,  m0);
  STAGE(1,0,0,0, Bt, n0); STAGE(1,1,0,0, Bt, n0);
  STAGE(1,0,1,1, Bt, n0); STAGE(1,1,1,1, Bt, n0);
  asm volatile("s_waitcnt vmcnt(4)" ::: "memory");
  __builtin_amdgcn_s_barrier();

  short8 bfrag[4][2];
  const u16* lA0 = &lds[0][0][(wm*128 + lr)*64];
  const u16* lB0 = &lds[0][1][(wn*64  + lr)*64];
  const u16* lA1 = &lds[1][0][(wm*128 + lr)*64];
  const u16* lB1 = &lds[1][1][(wn*64  + lr)*64];

  #define PHASE(lA_, lB_, jp_, RB_, VM_, ...)                                  \
    do {                                                                       \
      short8 a0k0 = *(const short8*)((lA_) + ((jp_)*32     )*64 + slot0);      \
      short8 a0k1 = *(const short8*)((lA_) + ((jp_)*32     )*64 + slot1);      \
      short8 a1k0 = *(const short8*)((lA_) + ((jp_)*32 + 16)*64 + slot0);      \
      short8 a1k1 = *(const short8*)((lA_) + ((jp_)*32 + 16)*64 + slot1);      \
      if (RB_) {                                                               \
        _Pragma("unroll")                                                      \
        for (int ni=0; ni<4; ++ni) {                                           \
          bfrag[ni][0] = *(const short8*)((lB_) + ni*16*64 + slot0);           \
          bfrag[ni][1] = *(const short8*)((lB_) + ni*16*64 + slot1);           \
        }                                                                      \
      }                                                                        \
      __VA_ARGS__;                                                             \
      __builtin_amdgcn_s_barrier();                                            \
      asm volatile("s_waitcnt lgkmcnt(0)" ::: "memory");                       \
      __builtin_amdgcn_sched_barrier(0);                                       \
      __builtin_amdgcn_s_setprio(1);                                           \
      _Pragma("unroll")                                                        \
      for (int ni=0; ni<4; ++ni) {                                             \
        acc[2*(jp_)  ][ni] = __builtin_amdgcn_mfma_f32_16x16x32_bf16(a0k0, bfrag[ni][0], acc[2*(jp_)  ][ni], 0,0,0); \
        acc[2*(jp_)  ][ni] = __builtin_amdgcn_mfma_f32_16x16x32_bf16(a0k1, bfrag[ni][1], acc[2*(jp_)  ][ni], 0,0,0); \
        acc[2*(jp_)+1][ni] = __builtin_amdgcn_mfma_f32_16x16x32_bf16(a1k0, bfrag[ni][0], acc[2*(jp_)+1][ni], 0,0,0); \
        acc[2*(jp_)+1][ni] = __builtin_amdgcn_mfma_f32_16x16x32_bf16(a1k1, bfrag[ni][1], acc[2*(jp_)+1][ni], 0,0,0); \
      }                                                                        \
      __builtin_amdgcn_s_setprio(0);                                           \
      VM_;                                                                     \
      __builtin_amdgcn_s_barrier();                                            \
    } while(0)

  #define VM4 asm volatile("s_waitcnt vmcnt(4)" ::: "memory")
  #define NOVM ((void)0)

  const int NITER = NT >> 1;
  for (int i = 0; i < NITER; ++i) {
    const int bt = 2*i + 1;
    const int a2 = (2*i+2 < NT) ? 2*i+2 : NT-1;
    const int b2 = (bt +2 < NT) ? bt +2 : NT-1;
    PHASE(lA0, lB0, 0, 1, NOVM, STAGE(0,0,bt,1, A, m0); STAGE(0,1,bt,1, A, m0));
    PHASE(lA0, lB0, 1, 0, NOVM, STAGE(1,0,a2,0, Bt, n0));
    PHASE(lA0, lB0, 2, 0, NOVM, STAGE(1,1,a2,0, Bt, n0));
    PHASE(lA0, lB0, 3, 0, VM4 , );
    PHASE(lA1, lB1, 0, 1, NOVM, STAGE(0,0,a2,0, A, m0));
    PHASE(lA1, lB1, 1, 0, NOVM, STAGE(0,1,a2,0, A, m0));
    PHASE(lA1, lB1, 2, 0, NOVM, STAGE(1,0,b2,1, Bt, n0));
    PHASE(lA1, lB1, 3, 0, VM4 , STAGE(1,1,b2,1, Bt, n0));
  }
  #undef PHASE
  #undef STAGE
  #undef VM4
  #undef NOVM

  // epilogue: D frag col=lane&15, row=(lane>>4)*4+reg; M-frag j linear.
  #pragma unroll
  for (int ni=0;ni<4;ni++){
    const int col = n0 + wn*64 + ni*16 + lr;
    const float bc = bias[col];
    #pragma unroll
    for (int j=0;j<8;j++){
      const int row0 = m0 + wm*128 + j*16 + (lane>>4)*4;
      #pragma unroll
      for (int r=0;r<4;r++)
        Cout[(size_t)(row0+r)*N + col] = f2bf(acc[j][ni][r] + bc);
    }
  }
}

// ---------------- 128x128 MFMA GEMM (kept for small GEMMs) -----------------
// OUT_KIND: 1 = f32 out, 2 = f32 out + residual
template<int OUT_KIND>
__global__ __launch_bounds__(256) void gemm_bt(
    const u16* __restrict__ A, const u16* __restrict__ Bt,
    const float* __restrict__ bias, const float* __restrict__ res,
    void* __restrict__ Cout, int M, int N, int K, int nbx)
{
  __shared__ u16 sA[128*32];
  __shared__ u16 sB[128*32];
  const int nwg = gridDim.x;
  const int q8 = nwg >> 3;
  const int bid = blockIdx.x;
  const int swz = (bid & 7) * q8 + (bid >> 3);
  const int bx = swz % nbx, by = swz / nbx;
  const int m0 = by * 128, n0 = bx * 128;
  const int t = threadIdx.x;
  const int w = t >> 6, lane = t & 63;
  const int wr = w >> 1, wc = w & 1;

  f32x4 acc[4][4];
  #pragma unroll
  for (int mi=0;mi<4;mi++)
    #pragma unroll
    for (int ni=0;ni<4;ni++)
      acc[mi][ni] = (f32x4){0.f,0.f,0.f,0.f};

  const int rST = w*32 + (lane>>2);
  const int cSRC = (((lane&3) ^ ((lane>>3)&3))) * 8;
  const u16* gA = A + (size_t)(m0 + rST)*K + cSRC;
  const u16* gB = Bt + (size_t)(n0 + rST)*K + cSRC;
  u16* lA = sA + (w*32)*32;
  u16* lB = sB + (w*32)*32;
  const int kc = lane >> 4;
  const int koff = (kc ^ (((lane&15)>>1)&3)) * 8;

  for (int k0 = 0; k0 < K; k0 += 32) {
    __syncthreads();
    __builtin_amdgcn_global_load_lds(GLOBAL_AS(gA),                LDS_AS(lA),          16, 0, 0);
    __builtin_amdgcn_global_load_lds(GLOBAL_AS(gA + 16*(size_t)K), LDS_AS(lA + 16*32),  16, 0, 0);
    __builtin_amdgcn_global_load_lds(GLOBAL_AS(gB),                LDS_AS(lB),          16, 0, 0);
    __builtin_amdgcn_global_load_lds(GLOBAL_AS(gB + 16*(size_t)K), LDS_AS(lB + 16*32),  16, 0, 0);
    gA += 32; gB += 32;
    __syncthreads();

    short8 af[4], bfr[4];
    #pragma unroll
    for (int mi=0;mi<4;mi++)
      af[mi] = *(const short8*)&sA[(wr*64 + mi*16 + (lane&15))*32 + koff];
    #pragma unroll
    for (int ni=0;ni<4;ni++)
      bfr[ni] = *(const short8*)&sB[(wc*64 + ni*16 + (lane&15))*32 + koff];
    #pragma unroll
    for (int mi=0;mi<4;mi++)
      #pragma unroll
      for (int ni=0;ni<4;ni++)
        acc[mi][ni] = __builtin_amdgcn_mfma_f32_16x16x32_bf16(af[mi], bfr[ni], acc[mi][ni], 0, 0, 0);
  }

  #pragma unroll
  for (int ni=0;ni<4;ni++){
    const int col = n0 + wc*64 + ni*16 + (lane&15);
    const float bc = bias[col];
    #pragma unroll
    for (int mi=0;mi<4;mi++){
      const int row0 = m0 + wr*64 + mi*16 + (lane>>4)*4;
      #pragma unroll
      for (int r=0;r<4;r++){
        float v = acc[mi][ni][r] + bc;
        size_t off = (size_t)(row0+r)*N + col;
        if constexpr (OUT_KIND == 1) ((float*)Cout)[off] = v;
        else                         ((float*)Cout)[off] = v + res[off];
      }
    }
  }
}

// ---------------- deformable sampling + attention-weighted accumulate ------
#define NQ_ 4096
#define LV_ 21504

__global__ __launch_bounds__(192) void sample_kernel(
    const float* __restrict__ offattn, const float* __restrict__ refp,
    const u16* __restrict__ value, u16* __restrict__ accb)
{
  __shared__ float s_w[2][4][72];
  __shared__ int   s_idx[2][4][72];
  __shared__ float s_at[2][72];
  const int t = threadIdx.x;

  if (t < 144) {
    const int qi = t / 72, s = t % 72;
    const int bq = blockIdx.x*2 + qi;
    const float* row = offattn + (size_t)bq * 256;
    const int j = s % 12, l = j >> 2;
    const float Wf = (l==0) ? 128.f : ((l==1) ? 64.f : 32.f);
    const int   Wi = (l==0) ? 128   : ((l==1) ? 64   : 32);
    const int   st = (l==0) ? 0     : ((l==1) ? 16384 : 20480);
    const float rx = refp[((size_t)bq*3 + l)*2 + 0];
    const float ry = refp[((size_t)bq*3 + l)*2 + 1];
    const float px = rx*Wf + row[2*s]   - 0.5f;
    const float py = ry*Wf + row[2*s+1] - 0.5f;
    const float x0f = floorf(px), y0f = floorf(py);
    const int x0 = (int)x0f, y0 = (int)y0f;
    const float fx = px - x0f, fy = py - y0f;
    #pragma unroll
    for (int c=0;c<4;c++){
      const int dx = c & 1, dy = c >> 1;
      const int ix = x0 + dx, iy = y0 + dy;
      const float wgt = (dx ? fx : 1.f-fx) * (dy ? fy : 1.f-fy);
      const bool ok = (ix >= 0) && (ix < Wi) && (iy >= 0) && (iy < Wi);
      const int cx = min(max(ix,0),Wi-1), cy = min(max(iy,0),Wi-1);
      s_w[qi][c][s]   = ok ? wgt : 0.f;
      s_idx[qi][c][s] = st + cy*Wi + cx;
    }
  } else if (t < 156) {
    const int u = t - 144, qi = u / 6, h = u % 6;
    const int bq = blockIdx.x*2 + qi;
    const float* lg = offattn + (size_t)bq * 256 + 144 + h*12;
    float m = lg[0];
    #pragma unroll
    for (int j2=1;j2<12;j2++) m = fmaxf(m, lg[j2]);
    float e[12]; float sum = 0.f;
    #pragma unroll
    for (int j2=0;j2<12;j2++){ e[j2] = __expf(lg[j2]-m); sum += e[j2]; }
    const float inv = 1.f/sum;
    #pragma unroll
    for (int j2=0;j2<12;j2++) s_at[qi][h*12+j2] = e[j2]*inv;
  }
  __syncthreads();

  const int qi = t / 96, tt = t % 96;
  const int bq = blockIdx.x*2 + qi;
  const int b = bq >> 12;
  const int cb = tt * 8;
  const int h = cb >> 7;
  const u16* vb = value + (size_t)b * LV_ * 768;

  float ax[8];
  #pragma unroll
  for (int k=0;k<8;k++) ax[k] = 0.f;

  #pragma unroll 2
  for (int j2=0;j2<12;j2++){
    const int s = h*12 + j2;
    const float at = s_at[qi][s];
    float sx[8];
    #pragma unroll
    for (int k=0;k<8;k++) sx[k] = 0.f;
    #pragma unroll
    for (int c=0;c<4;c++){
      const float wgt = s_w[qi][c][s];
      const u32x4 u = *(const u32x4*)(vb + (size_t)s_idx[qi][c][s]*768 + cb);
      sx[0] += wgt * lo16(u[0]); sx[1] += wgt * hi16(u[0]);
      sx[2] += wgt * lo16(u[1]); sx[3] += wgt * hi16(u[1]);
      sx[4] += wgt * lo16(u[2]); sx[5] += wgt * hi16(u[2]);
      sx[6] += wgt * lo16(u[3]); sx[7] += wgt * hi16(u[3]);
    }
    #pragma unroll
    for (int k=0;k<8;k++) ax[k] += at * sx[k];
  }

  u16* ob = accb + (size_t)bq * 768 + cb;
  u32x4 o;
  #pragma unroll
  for (int k=0;k<4;k++)
    o[k] = ((uint32_t)f2bf(ax[2*k+1]) << 16) | (uint32_t)f2bf(ax[2*k]);
  *(u32x4*)ob = o;
}

// ---------------------------------------------------------------------------
extern "C" void kernel_launch(void* const* d_in, const int* in_sizes, int n_in,
                              void* d_out, int out_size, void* d_ws, size_t ws_size,
                              hipStream_t stream) {
  (void)in_sizes; (void)n_in; (void)out_size; (void)ws_size;
  const float* query = (const float*)d_in[0];
  const float* refp  = (const float*)d_in[1];
  const float* feat  = (const float*)d_in[2];
  const float* qn_g  = (const float*)d_in[3];
  const float* qn_b  = (const float*)d_in[4];
  const float* fn_g  = (const float*)d_in[5];
  const float* fn_b  = (const float*)d_in[6];
  const float* Wv    = (const float*)d_in[7];
  const float* bv    = (const float*)d_in[8];
  const float* Ws    = (const float*)d_in[9];
  const float* bs    = (const float*)d_in[10];
  const float* Wa    = (const float*)d_in[11];
  const float* ba    = (const float*)d_in[12];
  const float* Wo    = (const float*)d_in[13];
  const float* bo    = (const float*)d_in[14];
  float* out = (float*)d_out;

  constexpr size_t SZ_FLN  = (size_t)43008*768*2;
  constexpr size_t SZ_QLN  = (size_t)8192*768*2;
  constexpr size_t SZ_W    = (size_t)768*768*2;
  constexpr size_t SZ_WSAT = (size_t)256*768*2;
  char* ws = (char*)d_ws;
  u16*  fln   = (u16*)(ws);
  u16*  value = (u16*)(ws + SZ_FLN);
  u16*  qln   = (u16*)(ws + 2*SZ_FLN);
  u16*  Wvt   = (u16*)(ws + 2*SZ_FLN + SZ_QLN);
  u16*  Wot   = (u16*)(ws + 2*SZ_FLN + SZ_QLN + SZ_W);
  u16*  Wsat  = (u16*)(ws + 2*SZ_FLN + SZ_QLN + 2*SZ_W);
  float* bsa  = (float*)(ws + 2*SZ_FLN + SZ_QLN + 2*SZ_W + SZ_WSAT);
  float* offattn = (float*)fln;
  u16*   accb    = qln;

  // 1) LayerNorms -> bf16
  ln_cast<<<8192, 256, 0, stream>>>(query, qn_g, qn_b, qln);
  ln_cast<<<43008, 256, 0, stream>>>(feat, fn_g, fn_b, fln);

  // 2) weight pre-transpose/cast
  tcast<<<dim3(24,24), 256, 0, stream>>>(Wv, 768, 768, Wvt);
  tcast<<<dim3(24,24), 256, 0, stream>>>(Wo, 768, 768, Wot);
  hipMemsetAsync(Wsat, 0, SZ_WSAT, stream);
  tcast<<<dim3(5,24), 256, 0, stream>>>(Ws, 144, 144, Wsat);
  tcast<<<dim3(3,24), 256, 0, stream>>>(Wa, 72, 72, Wsat + (size_t)144*768);
  pack_bsa<<<1, 256, 0, stream>>>(bs, ba, bsa);

  // 3) value = LN(feat) @ Wv + bv -> bf16 [43008, 768]   (168x3 = 504 blocks)
  gemm8<<<504, 512, 0, stream>>>(fln, Wvt, bv, value, 43008, 768, 768, 3);

  // 4) off/attn logits = LN(query) @ [Ws|Wa] -> f32 [8192, 256]
  gemm_bt<1><<<128, 256, 0, stream>>>(qln, Wsat, bsa, nullptr, offattn, 8192, 256, 768, 2);

  // 5) deformable sampling -> bf16 [8192, 768]
  sample_kernel<<<4096, 192, 0, stream>>>(offattn, refp, value, accb);

  // 6) out = acc @ Wo + bo + query -> f32
  gemm_bt<2><<<384, 256, 0, stream>>>(accb, Wot, bo, query, out, 8192, 768, 768, 6);
}

// Round 6
// 232.367 us; speedup vs baseline: 1.4761x; 1.0256x over previous
//
#include <hip/hip_runtime.h>
#include <cstdint>
#include <cstddef>

typedef unsigned short u16;
typedef __attribute__((ext_vector_type(8))) short short8;
typedef __attribute__((ext_vector_type(4))) float f32x4;
typedef __attribute__((ext_vector_type(4))) unsigned int u32x4;

#define GLOBAL_AS(p) ((const __attribute__((address_space(1))) void*)(p))
#define LDS_AS(p)    ((__attribute__((address_space(3))) void*)(p))

__device__ __forceinline__ float bf2f(u16 u){
  union { uint32_t u; float f; } c; c.u = ((uint32_t)u) << 16; return c.f;
}
__device__ __forceinline__ float lo16(uint32_t u){
  union { uint32_t u; float f; } c; c.u = u << 16; return c.f;
}
__device__ __forceinline__ float hi16(uint32_t u){
  union { uint32_t u; float f; } c; c.u = u & 0xffff0000u; return c.f;
}
__device__ __forceinline__ u16 f2bf(float f){
  union { float f; uint32_t u; } c; c.f = f;
  uint32_t r = c.u + 0x7fffu + ((c.u >> 16) & 1u);
  return (u16)(r >> 16);
}

// ---------------- LayerNorm + cast to bf16 (one block per 768-elem row) ----
__global__ __launch_bounds__(256) void ln_cast(const float* __restrict__ x,
    const float* __restrict__ g, const float* __restrict__ bta,
    u16* __restrict__ y)
{
  const size_t row = blockIdx.x;
  const float* xr = x + row * 768;
  const int t = threadIdx.x;
  float v0 = xr[t], v1 = xr[t+256], v2 = xr[t+512];
  float s = v0+v1+v2;
  float q = v0*v0 + v1*v1 + v2*v2;
  #pragma unroll
  for (int o=1;o<64;o<<=1){ s += __shfl_xor(s,o); q += __shfl_xor(q,o); }
  __shared__ float rs_[4], rq_[4];
  if ((t & 63) == 0){ rs_[t>>6] = s; rq_[t>>6] = q; }
  __syncthreads();
  s = rs_[0]+rs_[1]+rs_[2]+rs_[3];
  q = rq_[0]+rq_[1]+rq_[2]+rq_[3];
  const float m = s * (1.f/768.f);
  const float var = q * (1.f/768.f) - m*m;
  const float rstd = rsqrtf(var + 1e-6f);
  u16* yr = y + row * 768;
  yr[t]     = f2bf((v0-m)*rstd*g[t]     + bta[t]);
  yr[t+256] = f2bf((v1-m)*rstd*g[t+256] + bta[t+256]);
  yr[t+512] = f2bf((v2-m)*rstd*g[t+512] + bta[t+512]);
}

// ---------------- transpose+cast: out[n][k] = bf16(in[k*ld + n]), k<768 ----
__global__ __launch_bounds__(256) void tcast(const float* __restrict__ in,
    int ld, int ncnt, u16* __restrict__ out)
{
  __shared__ float tile[32][33];
  const int tx = threadIdx.x & 31, ty = threadIdx.x >> 5;
  const int n0 = blockIdx.x * 32, k0 = blockIdx.y * 32;
  #pragma unroll
  for (int i=0;i<4;i++){
    int k = k0 + ty + 8*i, n = n0 + tx;
    tile[ty+8*i][tx] = (n < ncnt) ? in[(size_t)k*ld + n] : 0.f;
  }
  __syncthreads();
  #pragma unroll
  for (int i=0;i<4;i++){
    int n = n0 + ty + 8*i, k = k0 + tx;
    if (n < ncnt) out[(size_t)n*768 + k] = f2bf(tile[tx][ty+8*i]);
  }
}

__global__ void pack_bsa(const float* __restrict__ bs, const float* __restrict__ ba,
                         float* __restrict__ bsa)
{
  int t = threadIdx.x;
  bsa[t] = (t < 144) ? bs[t] : ((t < 216) ? ba[t-144] : 0.f);
}

// ================== 8-phase pipelined 256x256 MFMA GEMM (v2) ===============
// BK=64, 512 threads = 8 waves (2M x 4N), per-wave C = 128x64 (8 M-frags).
// v2: register-load software pipeline -- phase p+1's A-quad ds_reads issue
// AFTER phase p's lgkmcnt(0)+sched_barrier, flying DURING p's MFMA burst.
// Only tile-start phases (p0/p4: 8 B-reads + quad0) are cold. One closing
// barrier per phase (open barriers dropped; WAR safety carried by closing
// barriers + vmcnt checkpoints). Stage ledger identical to R4 (proven):
//   p0: A(b)x2->buf1 | p1: B0(a+2)->buf0 | p2: B1(a+2) | p3: VM4
//   p4: A0(a+2)->buf0 | p5: A1(a+2) | p6: B0(b+2)->buf1 | p7: B1(b+2), VM4
// vmcnt(4) leaves 2 half-tiles in flight; never 0 in loop.
// Epilogue: restage C through LDS (loop buffers dead after vmcnt(0)+bar)
// for fully-coalesced 1KB/wave stores (kills 2x HBM write amplification).
__global__ __launch_bounds__(512, 2) void gemm8(
    const u16* __restrict__ A, const u16* __restrict__ Bt,
    const float* __restrict__ bias,
    u16* __restrict__ Cout, int M, int N, int K, int nbx)
{
  __shared__ u16 lds[2][2][256*64];
  const int nwg = gridDim.x;                       // multiple of 8
  const int bid = blockIdx.x;
  const int swz = (bid & 7) * (nwg >> 3) + (bid >> 3);
  const int bx = swz % nbx, by = swz / nbx;
  const int m0 = by*256, n0 = bx*256;
  const int t = threadIdx.x, w = t >> 6, lane = t & 63;
  const int wm = w >> 2, wn = w & 3;
  const int NT = K >> 6;
  const int lr = lane & 15, r7 = lane & 7;

  // staging: half-tile (128x64) = 2 gload_lds(16B)/thread; lane l -> row
  // (w*8 + l>>3)+{0,64}, chunk l&7; source chunk pre-swizzled (lane-linear
  // LDS write): c_src = (l&7) ^ ((l>>3)&7).
  const int stRow  = (w << 3) + (lane >> 3);
  const int stColU = (((lane & 7) ^ ((lane >> 3) & 7)) << 3);

  f32x4 acc[8][4];
  #pragma unroll
  for (int j=0;j<8;j++)
    #pragma unroll
    for (int ni=0;ni<4;ni++)
      acc[j][ni] = (f32x4){0.f,0.f,0.f,0.f};

  #define STAGE(op, half, kt, buf, G, gbase)                                   \
    { const u16* gsrc_ = (G) + (size_t)((gbase) + (half)*128 + stRow)*K        \
                              + (kt)*64 + stColU;                              \
      u16* l_ = &lds[buf][op][((half)*128 + (w<<3))*64];                       \
      __builtin_amdgcn_global_load_lds(GLOBAL_AS(gsrc_), LDS_AS(l_), 16,0,0);  \
      __builtin_amdgcn_global_load_lds(GLOBAL_AS(gsrc_ + (size_t)64*K),        \
                                       LDS_AS(l_ + 64*64), 16,0,0); }

  // read-side swizzle: chunk c at row R lives in slot c ^ (R&7)
  const int slot0 = ((0 + (lane>>4)) ^ r7) * 8;     // kk=0
  const int slot1 = ((4 + (lane>>4)) ^ r7) * 8;     // kk=1

  // prologue: A(0),B(0)->buf0 (8 loads); B(1)->buf1 (4). vmcnt(4) -> A0,B0 in.
  STAGE(0,0,0,0, A,  m0); STAGE(0,1,0,0, A,  m0);
  STAGE(1,0,0,0, Bt, n0); STAGE(1,1,0,0, Bt, n0);
  STAGE(1,0,1,1, Bt, n0); STAGE(1,1,1,1, Bt, n0);
  asm volatile("s_waitcnt vmcnt(4)" ::: "memory");
  __builtin_amdgcn_s_barrier();

  const u16* lA0 = &lds[0][0][(wm*128 + lr)*64];
  const u16* lB0 = &lds[0][1][(wn*64  + lr)*64];
  const u16* lA1 = &lds[1][0][(wm*128 + lr)*64];
  const u16* lB1 = &lds[1][1][(wn*64  + lr)*64];

  short8 bf_[4][2], aX[4], aY[4];

  #define READ_A(dst_, lA_, jp_)                                               \
    dst_[0] = *(const short8*)((lA_) + ((jp_)*32     )*64 + slot0);            \
    dst_[1] = *(const short8*)((lA_) + ((jp_)*32     )*64 + slot1);            \
    dst_[2] = *(const short8*)((lA_) + ((jp_)*32 + 16)*64 + slot0);            \
    dst_[3] = *(const short8*)((lA_) + ((jp_)*32 + 16)*64 + slot1);

  #define READ_B(lB_)                                                          \
    _Pragma("unroll")                                                          \
    for (int ni=0; ni<4; ++ni) {                                               \
      bf_[ni][0] = *(const short8*)((lB_) + ni*16*64 + slot0);                 \
      bf_[ni][1] = *(const short8*)((lB_) + ni*16*64 + slot1);                 \
    }

  #define MFMA16(aR_, jp_)                                                     \
    _Pragma("unroll")                                                          \
    for (int ni=0; ni<4; ++ni) {                                               \
      acc[2*(jp_)  ][ni] = __builtin_amdgcn_mfma_f32_16x16x32_bf16(aR_[0], bf_[ni][0], acc[2*(jp_)  ][ni], 0,0,0); \
      acc[2*(jp_)  ][ni] = __builtin_amdgcn_mfma_f32_16x16x32_bf16(aR_[1], bf_[ni][1], acc[2*(jp_)  ][ni], 0,0,0); \
      acc[2*(jp_)+1][ni] = __builtin_amdgcn_mfma_f32_16x16x32_bf16(aR_[2], bf_[ni][0], acc[2*(jp_)+1][ni], 0,0,0); \
      acc[2*(jp_)+1][ni] = __builtin_amdgcn_mfma_f32_16x16x32_bf16(aR_[3], bf_[ni][1], acc[2*(jp_)+1][ni], 0,0,0); \
    }

  #define LGKM0 do { asm volatile("s_waitcnt lgkmcnt(0)" ::: "memory");        \
                     __builtin_amdgcn_sched_barrier(0); } while(0)
  #define BAR   __builtin_amdgcn_s_barrier()
  #define VM4   asm volatile("s_waitcnt vmcnt(4)" ::: "memory")
  #define SETP1 __builtin_amdgcn_s_setprio(1)
  #define SETP0 __builtin_amdgcn_s_setprio(0)

  const int NITER = NT >> 1;
  for (int i = 0; i < NITER; ++i) {
    const int bt = 2*i + 1;
    const int a2 = (2*i+2 < NT) ? 2*i+2 : NT-1;
    const int b2 = (bt +2 < NT) ? bt +2 : NT-1;

    // ---- tile a (buf0) ----
    READ_B(lB0); READ_A(aX, lA0, 0);                 // p0 cold: 12 reads
    STAGE(0,0,bt,1, A, m0); STAGE(0,1,bt,1, A, m0);
    LGKM0;
    READ_A(aY, lA0, 1);                              // prefetch q1 under MFMA
    SETP1; MFMA16(aX, 0); SETP0;
    BAR;

    STAGE(1,0,a2,0, Bt, n0);                         // p1
    LGKM0;
    READ_A(aX, lA0, 2);
    SETP1; MFMA16(aY, 1); SETP0;
    BAR;

    STAGE(1,1,a2,0, Bt, n0);                         // p2
    LGKM0;
    READ_A(aY, lA0, 3);
    SETP1; MFMA16(aX, 2); SETP0;
    BAR;

    LGKM0;                                           // p3
    SETP1; MFMA16(aY, 3); SETP0;
    VM4; BAR;                                        // buf1 (tile b) ready

    // ---- tile b (buf1) ----
    READ_B(lB1); READ_A(aX, lA1, 0);                 // p4 cold
    STAGE(0,0,a2,0, A, m0);
    LGKM0;
    READ_A(aY, lA1, 1);
    SETP1; MFMA16(aX, 0); SETP0;
    BAR;

    STAGE(0,1,a2,0, A, m0);                          // p5
    LGKM0;
    READ_A(aX, lA1, 2);
    SETP1; MFMA16(aY, 1); SETP0;
    BAR;

    STAGE(1,0,b2,1, Bt, n0);                         // p6
    LGKM0;
    READ_A(aY, lA1, 3);
    SETP1; MFMA16(aX, 2); SETP0;
    BAR;

    STAGE(1,1,b2,1, Bt, n0);                         // p7
    LGKM0;
    SETP1; MFMA16(aY, 3); SETP0;
    VM4; BAR;                                        // buf0 (tile a+2) ready
  }
  #undef STAGE
  #undef READ_A
  #undef READ_B
  #undef MFMA16
  #undef LGKM0
  #undef VM4

  // ---- epilogue: restage C through LDS for coalesced stores ----
  asm volatile("s_waitcnt vmcnt(0)" ::: "memory");   // drain tail stages
  BAR;                                               // LDS now dead -> reuse
  u16* lsc = (u16*)lds;                              // 256x256 u16 = 128 KiB
  #pragma unroll
  for (int ni=0;ni<4;ni++){
    const int col = wn*64 + ni*16 + lr;
    const float bc = bias[n0 + col];
    #pragma unroll
    for (int j=0;j<8;j++){
      const int row0 = wm*128 + j*16 + (lane>>4)*4;
      #pragma unroll
      for (int r=0;r<4;r++)
        lsc[(row0+r)*256 + col] = f2bf(acc[j][ni][r] + bc);
    }
  }
  BAR;
  #pragma unroll
  for (int it=0; it<16; ++it){
    const int c = t + 512*it;                        // 16B chunk id
    const int row = c >> 5, col8 = (c & 31) << 3;
    u32x4 v = *(const u32x4*)(lsc + ((size_t)c << 3));
    *(u32x4*)(&Cout[(size_t)(m0 + row)*N + n0 + col8]) = v;
  }
  #undef BAR
  #undef SETP1
  #undef SETP0
}

// ---------------- 128x128 MFMA GEMM (kept for small GEMMs) -----------------
// OUT_KIND: 1 = f32 out, 2 = f32 out + residual
template<int OUT_KIND>
__global__ __launch_bounds__(256) void gemm_bt(
    const u16* __restrict__ A, const u16* __restrict__ Bt,
    const float* __restrict__ bias, const float* __restrict__ res,
    void* __restrict__ Cout, int M, int N, int K, int nbx)
{
  __shared__ u16 sA[128*32];
  __shared__ u16 sB[128*32];
  const int nwg = gridDim.x;
  const int q8 = nwg >> 3;
  const int bid = blockIdx.x;
  const int swz = (bid & 7) * q8 + (bid >> 3);
  const int bx = swz % nbx, by = swz / nbx;
  const int m0 = by * 128, n0 = bx * 128;
  const int t = threadIdx.x;
  const int w = t >> 6, lane = t & 63;
  const int wr = w >> 1, wc = w & 1;

  f32x4 acc[4][4];
  #pragma unroll
  for (int mi=0;mi<4;mi++)
    #pragma unroll
    for (int ni=0;ni<4;ni++)
      acc[mi][ni] = (f32x4){0.f,0.f,0.f,0.f};

  const int rST = w*32 + (lane>>2);
  const int cSRC = (((lane&3) ^ ((lane>>3)&3))) * 8;
  const u16* gA = A + (size_t)(m0 + rST)*K + cSRC;
  const u16* gB = Bt + (size_t)(n0 + rST)*K + cSRC;
  u16* lA = sA + (w*32)*32;
  u16* lB = sB + (w*32)*32;
  const int kc = lane >> 4;
  const int koff = (kc ^ (((lane&15)>>1)&3)) * 8;

  for (int k0 = 0; k0 < K; k0 += 32) {
    __syncthreads();
    __builtin_amdgcn_global_load_lds(GLOBAL_AS(gA),                LDS_AS(lA),          16, 0, 0);
    __builtin_amdgcn_global_load_lds(GLOBAL_AS(gA + 16*(size_t)K), LDS_AS(lA + 16*32),  16, 0, 0);
    __builtin_amdgcn_global_load_lds(GLOBAL_AS(gB),                LDS_AS(lB),          16, 0, 0);
    __builtin_amdgcn_global_load_lds(GLOBAL_AS(gB + 16*(size_t)K), LDS_AS(lB + 16*32),  16, 0, 0);
    gA += 32; gB += 32;
    __syncthreads();

    short8 af[4], bfr[4];
    #pragma unroll
    for (int mi=0;mi<4;mi++)
      af[mi] = *(const short8*)&sA[(wr*64 + mi*16 + (lane&15))*32 + koff];
    #pragma unroll
    for (int ni=0;ni<4;ni++)
      bfr[ni] = *(const short8*)&sB[(wc*64 + ni*16 + (lane&15))*32 + koff];
    #pragma unroll
    for (int mi=0;mi<4;mi++)
      #pragma unroll
      for (int ni=0;ni<4;ni++)
        acc[mi][ni] = __builtin_amdgcn_mfma_f32_16x16x32_bf16(af[mi], bfr[ni], acc[mi][ni], 0, 0, 0);
  }

  #pragma unroll
  for (int ni=0;ni<4;ni++){
    const int col = n0 + wc*64 + ni*16 + (lane&15);
    const float bc = bias[col];
    #pragma unroll
    for (int mi=0;mi<4;mi++){
      const int row0 = m0 + wr*64 + mi*16 + (lane>>4)*4;
      #pragma unroll
      for (int r=0;r<4;r++){
        float v = acc[mi][ni][r] + bc;
        size_t off = (size_t)(row0+r)*N + col;
        if constexpr (OUT_KIND == 1) ((float*)Cout)[off] = v;
        else                         ((float*)Cout)[off] = v + res[off];
      }
    }
  }
}

// ---------------- deformable sampling + attention-weighted accumulate ------
#define NQ_ 4096
#define LV_ 21504

__global__ __launch_bounds__(192) void sample_kernel(
    const float* __restrict__ offattn, const float* __restrict__ refp,
    const u16* __restrict__ value, u16* __restrict__ accb)
{
  __shared__ float s_w[2][4][72];
  __shared__ int   s_idx[2][4][72];
  __shared__ float s_at[2][72];
  const int t = threadIdx.x;

  if (t < 144) {
    const int qi = t / 72, s = t % 72;
    const int bq = blockIdx.x*2 + qi;
    const float* row = offattn + (size_t)bq * 256;
    const int j = s % 12, l = j >> 2;
    const float Wf = (l==0) ? 128.f : ((l==1) ? 64.f : 32.f);
    const int   Wi = (l==0) ? 128   : ((l==1) ? 64   : 32);
    const int   st = (l==0) ? 0     : ((l==1) ? 16384 : 20480);
    const float rx = refp[((size_t)bq*3 + l)*2 + 0];
    const float ry = refp[((size_t)bq*3 + l)*2 + 1];
    const float px = rx*Wf + row[2*s]   - 0.5f;
    const float py = ry*Wf + row[2*s+1] - 0.5f;
    const float x0f = floorf(px), y0f = floorf(py);
    const int x0 = (int)x0f, y0 = (int)y0f;
    const float fx = px - x0f, fy = py - y0f;
    #pragma unroll
    for (int c=0;c<4;c++){
      const int dx = c & 1, dy = c >> 1;
      const int ix = x0 + dx, iy = y0 + dy;
      const float wgt = (dx ? fx : 1.f-fx) * (dy ? fy : 1.f-fy);
      const bool ok = (ix >= 0) && (ix < Wi) && (iy >= 0) && (iy < Wi);
      const int cx = min(max(ix,0),Wi-1), cy = min(max(iy,0),Wi-1);
      s_w[qi][c][s]   = ok ? wgt : 0.f;
      s_idx[qi][c][s] = st + cy*Wi + cx;
    }
  } else if (t < 156) {
    const int u = t - 144, qi = u / 6, h = u % 6;
    const int bq = blockIdx.x*2 + qi;
    const float* lg = offattn + (size_t)bq * 256 + 144 + h*12;
    float m = lg[0];
    #pragma unroll
    for (int j2=1;j2<12;j2++) m = fmaxf(m, lg[j2]);
    float e[12]; float sum = 0.f;
    #pragma unroll
    for (int j2=0;j2<12;j2++){ e[j2] = __expf(lg[j2]-m); sum += e[j2]; }
    const float inv = 1.f/sum;
    #pragma unroll
    for (int j2=0;j2<12;j2++) s_at[qi][h*12+j2] = e[j2]*inv;
  }
  __syncthreads();

  const int qi = t / 96, tt = t % 96;
  const int bq = blockIdx.x*2 + qi;
  const int b = bq >> 12;
  const int cb = tt * 8;
  const int h = cb >> 7;
  const u16* vb = value + (size_t)b * LV_ * 768;

  float ax[8];
  #pragma unroll
  for (int k=0;k<8;k++) ax[k] = 0.f;

  #pragma unroll 2
  for (int j2=0;j2<12;j2++){
    const int s = h*12 + j2;
    const float at = s_at[qi][s];
    float sx[8];
    #pragma unroll
    for (int k=0;k<8;k++) sx[k] = 0.f;
    #pragma unroll
    for (int c=0;c<4;c++){
      const float wgt = s_w[qi][c][s];
      const u32x4 u = *(const u32x4*)(vb + (size_t)s_idx[qi][c][s]*768 + cb);
      sx[0] += wgt * lo16(u[0]); sx[1] += wgt * hi16(u[0]);
      sx[2] += wgt * lo16(u[1]); sx[3] += wgt * hi16(u[1]);
      sx[4] += wgt * lo16(u[2]); sx[5] += wgt * hi16(u[2]);
      sx[6] += wgt * lo16(u[3]); sx[7] += wgt * hi16(u[3]);
    }
    #pragma unroll
    for (int k=0;k<8;k++) ax[k] += at * sx[k];
  }

  u16* ob = accb + (size_t)bq * 768 + cb;
  u32x4 o;
  #pragma unroll
  for (int k=0;k<4;k++)
    o[k] = ((uint32_t)f2bf(ax[2*k+1]) << 16) | (uint32_t)f2bf(ax[2*k]);
  *(u32x4*)ob = o;
}

// ---------------------------------------------------------------------------
extern "C" void kernel_launch(void* const* d_in, const int* in_sizes, int n_in,
                              void* d_out, int out_size, void* d_ws, size_t ws_size,
                              hipStream_t stream) {
  (void)in_sizes; (void)n_in; (void)out_size; (void)ws_size;
  const float* query = (const float*)d_in[0];
  const float* refp  = (const float*)d_in[1];
  const float* feat  = (const float*)d_in[2];
  const float* qn_g  = (const float*)d_in[3];
  const float* qn_b  = (const float*)d_in[4];
  const float* fn_g  = (const float*)d_in[5];
  const float* fn_b  = (const float*)d_in[6];
  const float* Wv    = (const float*)d_in[7];
  const float* bv    = (const float*)d_in[8];
  const float* Ws    = (const float*)d_in[9];
  const float* bs    = (const float*)d_in[10];
  const float* Wa    = (const float*)d_in[11];
  const float* ba    = (const float*)d_in[12];
  const float* Wo    = (const float*)d_in[13];
  const float* bo    = (const float*)d_in[14];
  float* out = (float*)d_out;

  constexpr size_t SZ_FLN  = (size_t)43008*768*2;
  constexpr size_t SZ_QLN  = (size_t)8192*768*2;
  constexpr size_t SZ_W    = (size_t)768*768*2;
  constexpr size_t SZ_WSAT = (size_t)256*768*2;
  char* ws = (char*)d_ws;
  u16*  fln   = (u16*)(ws);
  u16*  value = (u16*)(ws + SZ_FLN);
  u16*  qln   = (u16*)(ws + 2*SZ_FLN);
  u16*  Wvt   = (u16*)(ws + 2*SZ_FLN + SZ_QLN);
  u16*  Wot   = (u16*)(ws + 2*SZ_FLN + SZ_QLN + SZ_W);
  u16*  Wsat  = (u16*)(ws + 2*SZ_FLN + SZ_QLN + 2*SZ_W);
  float* bsa  = (float*)(ws + 2*SZ_FLN + SZ_QLN + 2*SZ_W + SZ_WSAT);
  float* offattn = (float*)fln;
  u16*   accb    = qln;

  // 1) LayerNorms -> bf16
  ln_cast<<<8192, 256, 0, stream>>>(query, qn_g, qn_b, qln);
  ln_cast<<<43008, 256, 0, stream>>>(feat, fn_g, fn_b, fln);

  // 2) weight pre-transpose/cast
  tcast<<<dim3(24,24), 256, 0, stream>>>(Wv, 768, 768, Wvt);
  tcast<<<dim3(24,24), 256, 0, stream>>>(Wo, 768, 768, Wot);
  hipMemsetAsync(Wsat, 0, SZ_WSAT, stream);
  tcast<<<dim3(5,24), 256, 0, stream>>>(Ws, 144, 144, Wsat);
  tcast<<<dim3(3,24), 256, 0, stream>>>(Wa, 72, 72, Wsat + (size_t)144*768);
  pack_bsa<<<1, 256, 0, stream>>>(bs, ba, bsa);

  // 3) value = LN(feat) @ Wv + bv -> bf16 [43008, 768]   (168x3 = 504 blocks)
  gemm8<<<504, 512, 0, stream>>>(fln, Wvt, bv, value, 43008, 768, 768, 3);

  // 4) off/attn logits = LN(query) @ [Ws|Wa] -> f32 [8192, 256]
  gemm_bt<1><<<128, 256, 0, stream>>>(qln, Wsat, bsa, nullptr, offattn, 8192, 256, 768, 2);

  // 5) deformable sampling -> bf16 [8192, 768]
  sample_kernel<<<4096, 192, 0, stream>>>(offattn, refp, value, accb);

  // 6) out = acc @ Wo + bo + query -> f32
  gemm_bt<2><<<384, 256, 0, stream>>>(accb, Wot, bo, query, out, 8192, 768, 768, 6);
}